// Round 7
// baseline (364.194 us; speedup 1.0000x reference)
//
#include <hip/hip_runtime.h>

// N=100000 nodes, E=1250000 edges, all dims 64.
// R16: R15 null result proved k_count is capped by DEVICE-SCOPE atomic
// throughput (~21.5 G/s, fabric-serialized). Fix: partition counting across
// the 8 per-XCD L2s — cnt8[8][N] replicas, block reads XCC_ID (hwreg 20),
// WORKGROUP-scope atomic_fetch_add (no sc1 -> executes in local XCD L2;
// coherent because only same-XCD blocks touch a replica; kernel-boundary
// flush publishes). rank packs (local_rank<<3)|xcd; scan computes totals +
// per-XCD absolute bases boff8; k_fill uses boff8 instead of offs (1:1 load).
// Gather/GEMM pipeline byte-identical to R14/R15 (334us best).

#define SCAN_CHUNK 2048

typedef __attribute__((ext_vector_type(8))) short short8;   // 8 bf16 = 4 VGPRs
typedef __attribute__((ext_vector_type(4))) short short4v;  // 4 bf16 = 2 VGPRs
typedef __attribute__((ext_vector_type(4))) float floatx4;  // MFMA C/D

__device__ __forceinline__ unsigned short f2bf(float f) {
    unsigned int u = __float_as_uint(f);
    unsigned int r = u + 0x7FFFu + ((u >> 16) & 1u);  // round-to-nearest-even
    return (unsigned short)(r >> 16);
}
__device__ __forceinline__ float bf2f(unsigned short h) {
    return __uint_as_float(((unsigned int)h) << 16);
}

__device__ __forceinline__ unsigned lds_addr(const void* p) {
    return (unsigned)(unsigned long long)(__attribute__((address_space(3))) const char*)p;
}

__device__ __forceinline__ int get_xcc() {
    int x;
    asm("s_getreg_b32 %0, hwreg(20, 0, 32)" : "=s"(x));  // HW_REG_XCC_ID (gfx94x+)
    return x & 7;
}

__device__ __forceinline__ short8 cat44(short4v lo, short4v hi) {
    short8 r;
    r[0] = lo[0]; r[1] = lo[1]; r[2] = lo[2]; r[3] = lo[3];
    r[4] = hi[0]; r[5] = hi[1]; r[6] = hi[2]; r[7] = hi[3];
    return r;
}

// Read 4 B-frags (col-tiles CTB..CTB+3) for this lane's k-group via HW transpose.
// LDS holds 32xROWSH bf16 tile subtiled [k/4][f/16][4][16]; subtile s at byte s*128.
// a0 = wb_base + (q*2*NF)*128 + (lane&15)*8.
template<int NF, int CTB>
__device__ __forceinline__ void tr_read4(unsigned a0, short8 bf[4]) {
    short4v l0, h0, l1, h1, l2, h2, l3, h3;
    asm volatile(
        "ds_read_b64_tr_b16 %0, %8 offset:%9\n\t"
        "ds_read_b64_tr_b16 %1, %8 offset:%10\n\t"
        "ds_read_b64_tr_b16 %2, %8 offset:%11\n\t"
        "ds_read_b64_tr_b16 %3, %8 offset:%12\n\t"
        "ds_read_b64_tr_b16 %4, %8 offset:%13\n\t"
        "ds_read_b64_tr_b16 %5, %8 offset:%14\n\t"
        "ds_read_b64_tr_b16 %6, %8 offset:%15\n\t"
        "ds_read_b64_tr_b16 %7, %8 offset:%16\n\t"
        "s_waitcnt lgkmcnt(0)"
        : "=&v"(l0), "=&v"(h0), "=&v"(l1), "=&v"(h1),
          "=&v"(l2), "=&v"(h2), "=&v"(l3), "=&v"(h3)
        : "v"(a0),
          "i"((0 * NF + CTB + 0) * 128), "i"((1 * NF + CTB + 0) * 128),
          "i"((0 * NF + CTB + 1) * 128), "i"((1 * NF + CTB + 1) * 128),
          "i"((0 * NF + CTB + 2) * 128), "i"((1 * NF + CTB + 2) * 128),
          "i"((0 * NF + CTB + 3) * 128), "i"((1 * NF + CTB + 3) * 128)
        : "memory");
    bf[0] = cat44(l0, h0);
    bf[1] = cat44(l1, h1);
    bf[2] = cat44(l2, h2);
    bf[3] = cat44(l3, h3);
}

// count into this XCD's replica (L2-local workgroup-scope atomics);
// rank packs (local_rank<<3)|xcd. Fused x->bf16 on spare threads.
__global__ void k_count(const int* __restrict__ ei, int E,
                        unsigned int* __restrict__ cnt8, int N,
                        int* __restrict__ rank,
                        const float* __restrict__ x, unsigned short* __restrict__ xb,
                        int xtotal, int do_x) {
    int xcd = get_xcc();
    unsigned int* myc = cnt8 + (size_t)xcd * N;
    int i = blockIdx.x * blockDim.x + threadIdx.x;
    int e = i * 8;
    if (e + 8 <= E) {
        int4 d0 = *(const int4*)&ei[E + e];
        int4 d1 = *(const int4*)&ei[E + e + 4];
        int4 r0, r1;
        r0.x = (int)__hip_atomic_fetch_add(&myc[d0.x], 1u, __ATOMIC_RELAXED, __HIP_MEMORY_SCOPE_WORKGROUP);
        r0.y = (int)__hip_atomic_fetch_add(&myc[d0.y], 1u, __ATOMIC_RELAXED, __HIP_MEMORY_SCOPE_WORKGROUP);
        r0.z = (int)__hip_atomic_fetch_add(&myc[d0.z], 1u, __ATOMIC_RELAXED, __HIP_MEMORY_SCOPE_WORKGROUP);
        r0.w = (int)__hip_atomic_fetch_add(&myc[d0.w], 1u, __ATOMIC_RELAXED, __HIP_MEMORY_SCOPE_WORKGROUP);
        r1.x = (int)__hip_atomic_fetch_add(&myc[d1.x], 1u, __ATOMIC_RELAXED, __HIP_MEMORY_SCOPE_WORKGROUP);
        r1.y = (int)__hip_atomic_fetch_add(&myc[d1.y], 1u, __ATOMIC_RELAXED, __HIP_MEMORY_SCOPE_WORKGROUP);
        r1.z = (int)__hip_atomic_fetch_add(&myc[d1.z], 1u, __ATOMIC_RELAXED, __HIP_MEMORY_SCOPE_WORKGROUP);
        r1.w = (int)__hip_atomic_fetch_add(&myc[d1.w], 1u, __ATOMIC_RELAXED, __HIP_MEMORY_SCOPE_WORKGROUP);
        r0.x = (r0.x << 3) | xcd; r0.y = (r0.y << 3) | xcd;
        r0.z = (r0.z << 3) | xcd; r0.w = (r0.w << 3) | xcd;
        r1.x = (r1.x << 3) | xcd; r1.y = (r1.y << 3) | xcd;
        r1.z = (r1.z << 3) | xcd; r1.w = (r1.w << 3) | xcd;
        *(int4*)&rank[e] = r0;
        *(int4*)&rank[e + 4] = r1;
    } else if (e < E) {
        for (int j = e; j < E; ++j) {
            int rl = (int)__hip_atomic_fetch_add(&myc[ei[E + j]], 1u, __ATOMIC_RELAXED, __HIP_MEMORY_SCOPE_WORKGROUP);
            rank[j] = (rl << 3) | xcd;
        }
    }
    if (do_x) {
        int xe = i * 8;
        if (xe + 8 <= xtotal) {
            float4 a = *(const float4*)&x[xe];
            float4 b = *(const float4*)&x[xe + 4];
            short8 o;
            o[0] = (short)f2bf(a.x); o[1] = (short)f2bf(a.y);
            o[2] = (short)f2bf(a.z); o[3] = (short)f2bf(a.w);
            o[4] = (short)f2bf(b.x); o[5] = (short)f2bf(b.y);
            o[6] = (short)f2bf(b.z); o[7] = (short)f2bf(b.w);
            *(short8*)&xb[xe] = o;
        } else if (xe < xtotal) {
            for (int j = xe; j < xtotal; ++j) xb[j] = f2bf(x[j]);
        }
    }
}

// scan over (tot(i) + 1): tot = sum of 8 XCD replicas; one self slot per node
__global__ void k_scan_reduce(const unsigned int* __restrict__ cnt8, int N,
                              int* __restrict__ blockSums) {
    __shared__ int lds[256];
    int base = blockIdx.x * SCAN_CHUNK;
    int t = threadIdx.x;
    int s = 0;
    for (int j = 0; j < 8; ++j) {
        int idx = base + t * 8 + j;
        if (idx < N) {
            int tot = 0;
            #pragma unroll
            for (int k = 0; k < 8; ++k) tot += (int)cnt8[(size_t)k * N + idx];
            s += tot + 1;
        }
    }
    lds[t] = s;
    __syncthreads();
    for (int d = 128; d > 0; d >>= 1) {
        if (t < d) lds[t] += lds[t + d];
        __syncthreads();
    }
    if (t == 0) blockSums[blockIdx.x] = lds[0];
}

__global__ void k_scan_spine(int* __restrict__ blockSums, int B) {
    if (threadIdx.x == 0 && blockIdx.x == 0) {
        int run = 0;
        for (int b = 0; b < B; ++b) { int v = blockSums[b]; blockSums[b] = run; run += v; }
    }
}

// writes offs (incl. self slot), cnt totals, dinv, and per-XCD absolute bases boff8
__global__ void k_scan_write(const unsigned int* __restrict__ cnt8, int N,
                             const int* __restrict__ blockSums,
                             int* __restrict__ offs, int* __restrict__ cnt,
                             float* __restrict__ dinv, int* __restrict__ boff8) {
    __shared__ int lds[256];
    int base = blockIdx.x * SCAN_CHUNK;
    int t = threadIdx.x;
    int v[8];
    int s = 0;
    for (int j = 0; j < 8; ++j) {
        int idx = base + t * 8 + j;
        int tot = 0;
        if (idx < N) {
            #pragma unroll
            for (int k = 0; k < 8; ++k) tot += (int)cnt8[(size_t)k * N + idx];
        }
        v[j] = tot;
        s += (idx < N) ? tot + 1 : 0;
    }
    lds[t] = s;
    __syncthreads();
    for (int d = 1; d < 256; d <<= 1) {
        int x = (t >= d) ? lds[t - d] : 0;
        __syncthreads();
        lds[t] += x;
        __syncthreads();
    }
    int excl = (t == 0) ? 0 : lds[t - 1];
    int run = blockSums[blockIdx.x] + excl;
    for (int j = 0; j < 8; ++j) {
        int idx = base + t * 8 + j;
        if (idx < N) {
            offs[idx] = run;
            cnt[idx] = v[j];
            int acc = run;
            #pragma unroll
            for (int k = 0; k < 8; ++k) {
                boff8[(size_t)k * N + idx] = acc;
                acc += (int)cnt8[(size_t)k * N + idx];
            }
            run += v[j] + 1;
            dinv[idx] = rsqrtf((float)v[j] + 1.0f);
            if (idx == N - 1) offs[N] = run;  // total incl. self slots
        }
    }
}

// atomic-free fill (8 edges/thread): pos = boff8[xcd][dst] + local_rank;
// emits pk = (dst&15)<<16 | bf16(ew); fused self-loop write (thread i -> node i).
__global__ void k_fill(const int* __restrict__ ei, int E, const int* __restrict__ offs,
                       const int* __restrict__ rank, const int* __restrict__ cnt,
                       const int* __restrict__ boff8, int N,
                       const float* __restrict__ dinv,
                       int* __restrict__ csr, unsigned int* __restrict__ pk, int use_pk) {
    int i = blockIdx.x * blockDim.x + threadIdx.x;
    int e = i * 8;
    if (e + 8 <= E) {
        int4 s0 = *(const int4*)&ei[e];
        int4 s1 = *(const int4*)&ei[e + 4];
        int4 d0 = *(const int4*)&ei[E + e];
        int4 d1 = *(const int4*)&ei[E + e + 4];
        int4 r0 = *(const int4*)&rank[e];
        int4 r1 = *(const int4*)&rank[e + 4];
        int p0 = boff8[(size_t)(r0.x & 7) * N + d0.x] + (r0.x >> 3);
        int p1 = boff8[(size_t)(r0.y & 7) * N + d0.y] + (r0.y >> 3);
        int p2 = boff8[(size_t)(r0.z & 7) * N + d0.z] + (r0.z >> 3);
        int p3 = boff8[(size_t)(r0.w & 7) * N + d0.w] + (r0.w >> 3);
        int p4 = boff8[(size_t)(r1.x & 7) * N + d1.x] + (r1.x >> 3);
        int p5 = boff8[(size_t)(r1.y & 7) * N + d1.y] + (r1.y >> 3);
        int p6 = boff8[(size_t)(r1.z & 7) * N + d1.z] + (r1.z >> 3);
        int p7 = boff8[(size_t)(r1.w & 7) * N + d1.w] + (r1.w >> 3);
        csr[p0] = s0.x; csr[p1] = s0.y; csr[p2] = s0.z; csr[p3] = s0.w;
        csr[p4] = s1.x; csr[p5] = s1.y; csr[p6] = s1.z; csr[p7] = s1.w;
        if (use_pk) {
            pk[p0] = ((unsigned)(d0.x & 15) << 16) | f2bf(dinv[s0.x] * dinv[d0.x]);
            pk[p1] = ((unsigned)(d0.y & 15) << 16) | f2bf(dinv[s0.y] * dinv[d0.y]);
            pk[p2] = ((unsigned)(d0.z & 15) << 16) | f2bf(dinv[s0.z] * dinv[d0.z]);
            pk[p3] = ((unsigned)(d0.w & 15) << 16) | f2bf(dinv[s0.w] * dinv[d0.w]);
            pk[p4] = ((unsigned)(d1.x & 15) << 16) | f2bf(dinv[s1.x] * dinv[d1.x]);
            pk[p5] = ((unsigned)(d1.y & 15) << 16) | f2bf(dinv[s1.y] * dinv[d1.y]);
            pk[p6] = ((unsigned)(d1.z & 15) << 16) | f2bf(dinv[s1.z] * dinv[d1.z]);
            pk[p7] = ((unsigned)(d1.w & 15) << 16) | f2bf(dinv[s1.w] * dinv[d1.w]);
        }
    } else if (e < E) {
        for (int j = e; j < E; ++j) {
            int dd = ei[E + j];
            int r = rank[j];
            int p = boff8[(size_t)(r & 7) * N + dd] + (r >> 3);
            csr[p] = ei[j];
            if (use_pk) pk[p] = ((unsigned)(dd & 15) << 16) | f2bf(dinv[ei[j]] * dinv[dd]);
        }
    }
    if (use_pk && i < N) {
        int pos = offs[i] + cnt[i];
        float di = dinv[i];
        csr[pos] = i;
        pk[pos] = ((unsigned)(i & 15) << 16) | (1u << 20) | f2bf(di * di);
    }
}

// ===================== MFMA SpMM gather (serial, proven R10 structure) ========
// One wave per 16 dst nodes; 4 waves/block; no barriers. Edges incl. self-loops
// contiguous in [offs[base], offs[base+16)). Per 32-edge chunk: reg-stage 32 src
// rows -> conflict-free ds_write (lane L -> byte p*1024+16L of subtiled image),
// A-frags from resident meta regs via shfl, tr_read + 8 MFMAs.
template<int ROWSH>
__launch_bounds__(256)
__global__ void k_gatherM(const unsigned short* __restrict__ feat,
                          const int* __restrict__ csr,
                          const unsigned int* __restrict__ pk,
                          const int* __restrict__ offs, const int* __restrict__ cnt,
                          unsigned short* __restrict__ agg, int N) {
    constexpr int NF = ROWSH / 16;      // f-subtiles per edge row (4 or 8)
    constexpr int LPR = ROWSH / 8;      // lanes per staged row
    constexpr int EPP = 64 / LPR;       // edges per staging pass
    constexpr int PASSES = 32 / EPP;    // passes per 32-edge chunk (4 or 8)

    __shared__ unsigned short sbuf[4][32 * ROWSH];

    const int lane = threadIdx.x & 63;
    const int wv = threadIdx.x >> 6;
    const int base = blockIdx.x * 64 + wv * 16;
    if (base >= N) return;

    const int q = lane >> 4;
    const int d16 = lane & 15;

    // conflict-free staging map: lane L holds the 16B that belongs at byte
    // p*1024 + 16L of the subtiled LDS image (bijection per 1024B pass block).
    const int parity = lane & 1;
    const int ei_low = (lane >> 1) & 3;
    const int sf_sub = (lane >> 3) & (NF - 1);
    const int ei_high = (NF == 8) ? 0 : (lane >> 5);
    const int eid = ei_high * 4 + ei_low;
    const int sf = sf_sub * 16 + parity * 8;

    const int elo = offs[base];
    const int ehi = offs[min(base + 16, N)];
    const int emax = ehi - 1;
    const int nch = (ehi - elo + 31) >> 5;

    // ---- resident meta: 4 windows of 64 edges (covers 8 chunks = 256 edges) ----
    int cM0, cM1, cM2, cM3;
    unsigned pM0, pM1, pM2, pM3;
    {
        int i0 = elo + lane;
        int i1 = i0 + 64, i2 = i0 + 128, i3 = i0 + 192;
        cM0 = csr[i0 <= emax ? i0 : emax];
        cM1 = csr[i1 <= emax ? i1 : emax];
        cM2 = csr[i2 <= emax ? i2 : emax];
        cM3 = csr[i3 <= emax ? i3 : emax];
        unsigned t0 = pk[i0 <= emax ? i0 : emax];
        unsigned t1 = pk[i1 <= emax ? i1 : emax];
        unsigned t2 = pk[i2 <= emax ? i2 : emax];
        unsigned t3 = pk[i3 <= emax ? i3 : emax];
        pM0 = (i0 < ehi) ? t0 : 0x00100000u;
        pM1 = (i1 < ehi) ? t1 : 0x00100000u;
        pM2 = (i2 < ehi) ? t2 : 0x00100000u;
        pM3 = (i3 < ehi) ? t3 : 0x00100000u;
    }

    floatx4 accg[4], accs[4];
#pragma unroll
    for (int i = 0; i < 4; ++i) {
        accg[i] = floatx4{0.f, 0.f, 0.f, 0.f};
        accs[i] = floatx4{0.f, 0.f, 0.f, 0.f};
    }

    unsigned short* wb = &sbuf[wv][0];
    const unsigned a0 = lds_addr(wb) + (unsigned)(q * 2 * NF) * 128u + (unsigned)d16 * 8u;

    for (int c = 0; c < nch; ++c) {
        // ---- meta for chunk c (resident regs; rare dynamic path >256 edges) ----
        int cv; unsigned pv; int wofs;
        int rc = c >> 1;
        if (rc < 4) {
            wofs = (c & 1) << 5;
            cv = (rc == 0) ? cM0 : (rc == 1) ? cM1 : (rc == 2) ? cM2 : cM3;
            pv = (rc == 0) ? pM0 : (rc == 1) ? pM1 : (rc == 2) ? pM2 : pM3;
        } else {
            int idx = elo + (c << 5) + lane;
            int idc = idx <= emax ? idx : emax;
            cv = csr[idc];
            unsigned t = pk[idc];
            pv = (idx < ehi) ? t : 0x00100000u;
            wofs = 0;
        }

        // ---- issue row loads (addresses from resident regs, no meta loads) ----
        short8 stg[PASSES];
#pragma unroll
        for (int p = 0; p < PASSES; ++p) {
            int src = __shfl(cv, wofs + p * EPP + eid, 64);
            stg[p] = *(const short8*)&feat[(size_t)src * ROWSH + sf];
        }

        // ---- A-frags (register-only; overlaps load latency) ----
        short8 aG, aS;
#pragma unroll
        for (int j = 0; j < 8; ++j) {
            unsigned u = (unsigned)__shfl((int)pv, wofs + q * 8 + j, 64);
            unsigned hi = u >> 16;
            bool match = (int)(hi & 15u) == d16;
            aG[j] = match ? (short)(u & 0xFFFFu) : (short)0;
            aS[j] = (match && !(hi & 16u)) ? (short)0x3F80 : (short)0;
        }

        // ---- conflict-free ds_write (compiler inserts vmcnt waits for stg) ----
#pragma unroll
        for (int p = 0; p < PASSES; ++p)
            *(short8*)&wb[p * 512 + lane * 8] = stg[p];
        asm volatile("s_waitcnt lgkmcnt(0)" ::: "memory");
        __builtin_amdgcn_sched_barrier(0);

        // ---- tr_read + MFMA ----
        short8 bG[4];
        tr_read4<NF, 0>(a0, bG);
#pragma unroll
        for (int ct = 0; ct < 4; ++ct)
            accg[ct] = __builtin_amdgcn_mfma_f32_16x16x32_bf16(aG, bG[ct], accg[ct], 0, 0, 0);
        if constexpr (NF == 8) {
            short8 bS[4];
            tr_read4<NF, 4>(a0, bS);
#pragma unroll
            for (int ct = 0; ct < 4; ++ct)
                accs[ct] = __builtin_amdgcn_mfma_f32_16x16x32_bf16(aS, bS[ct], accs[ct], 0, 0, 0);
        } else {
#pragma unroll
            for (int ct = 0; ct < 4; ++ct)
                accs[ct] = __builtin_amdgcn_mfma_f32_16x16x32_bf16(aS, bG[ct], accs[ct], 0, 0, 0);
        }
    }

    // ---- epilogue: C/D layout row=(q*4+r), col=d16 ----
#pragma unroll
    for (int r = 0; r < 4; ++r) {
        int node = base + q * 4 + r;
        if (node < N) {
            float rn = 1.0f / fmaxf((float)cnt[node], 1.0f);
#pragma unroll
            for (int ct = 0; ct < 4; ++ct) {
                agg[(size_t)node * 128 + ct * 16 + d16]      = f2bf(accg[ct][r]);
                agg[(size_t)node * 128 + 64 + ct * 16 + d16] = f2bf(accs[ct][r] * rn);
            }
        }
    }
}

// ===================== fallback scalar gathers (ws-size guard) =====================
// NOTE: offs includes one self slot per node; fallbacks read only the first
// cnt[] entries of each node's range, so they remain correct.
__device__ __forceinline__ void xor_reduce8(float4& a, float4& b) {
    a.x += __shfl_xor(a.x, 16, 64); a.y += __shfl_xor(a.y, 16, 64);
    a.z += __shfl_xor(a.z, 16, 64); a.w += __shfl_xor(a.w, 16, 64);
    b.x += __shfl_xor(b.x, 16, 64); b.y += __shfl_xor(b.y, 16, 64);
    b.z += __shfl_xor(b.z, 16, 64); b.w += __shfl_xor(b.w, 16, 64);
    a.x += __shfl_xor(a.x, 32, 64); a.y += __shfl_xor(a.y, 32, 64);
    a.z += __shfl_xor(a.z, 32, 64); a.w += __shfl_xor(a.w, 32, 64);
    b.x += __shfl_xor(b.x, 32, 64); b.y += __shfl_xor(b.y, 32, 64);
    b.z += __shfl_xor(b.z, 32, 64); b.w += __shfl_xor(b.w, 32, 64);
}

__device__ __forceinline__ float red16(float v) {
    v += __shfl_xor(v, 1, 64);
    v += __shfl_xor(v, 2, 64);
    v += __shfl_xor(v, 4, 64);
    v += __shfl_xor(v, 8, 64);
    return v;
}

__global__ void k_gather1_f32(const float* __restrict__ x, const int* __restrict__ csr,
                              const int* __restrict__ offs, const int* __restrict__ cnt,
                              const float* __restrict__ dinv,
                              unsigned short* __restrict__ agg, int N) {
    int lane = threadIdx.x & 63;
    int wave = threadIdx.x >> 6;
    int node = blockIdx.x * 4 + wave;
    if (node >= N) return;
    int c = lane & 15, grp = lane >> 4;

    int st = offs[node];
    int cn = cnt[node];
    float di = dinv[node];

    float4 aA = {0.f, 0.f, 0.f, 0.f}, aB = {0.f, 0.f, 0.f, 0.f};
    for (int e = 0; e < cn; e += 8) {
        int i0 = e + grp, i1 = e + 4 + grp;
        float m0 = (i0 < cn) ? 1.f : 0.f;
        float m1 = (i1 < cn) ? 1.f : 0.f;
        int s0 = csr[st + (i0 < cn ? i0 : cn - 1)];
        int s1 = csr[st + (i1 < cn ? i1 : cn - 1)];
        float w0 = m0 * dinv[s0];
        float w1 = m1 * dinv[s1];
        float4 v0 = *(const float4*)&x[(size_t)s0 * 64 + 4 * c];
        float4 v1 = *(const float4*)&x[(size_t)s1 * 64 + 4 * c];
        aA.x += w0 * v0.x + w1 * v1.x; aA.y += w0 * v0.y + w1 * v1.y;
        aA.z += w0 * v0.z + w1 * v1.z; aA.w += w0 * v0.w + w1 * v1.w;
        aB.x += m0 * v0.x + m1 * v1.x; aB.y += m0 * v0.y + m1 * v1.y;
        aB.z += m0 * v0.z + m1 * v1.z; aB.w += m0 * v0.w + m1 * v1.w;
    }
    xor_reduce8(aA, aB);

    if (grp == 0) {
        float4 sq = *(const float4*)&x[(size_t)node * 64 + 4 * c];
        float d2 = di * di;
        ushort4 o;
        o.x = f2bf(di * aA.x + d2 * sq.x); o.y = f2bf(di * aA.y + d2 * sq.y);
        o.z = f2bf(di * aA.z + d2 * sq.z); o.w = f2bf(di * aA.w + d2 * sq.w);
        *(ushort4*)&agg[(size_t)node * 128 + 4 * c] = o;
    } else if (grp == 1) {
        float rn = 1.0f / fmaxf((float)cn, 1.0f);
        ushort4 o;
        o.x = f2bf(aB.x * rn); o.y = f2bf(aB.y * rn);
        o.z = f2bf(aB.z * rn); o.w = f2bf(aB.w * rn);
        *(ushort4*)&agg[(size_t)node * 128 + 64 + 4 * c] = o;
    }
}

__global__ void k_gather2(const unsigned short* __restrict__ gs, const int* __restrict__ csr,
                          const int* __restrict__ offs, const int* __restrict__ cnt,
                          const float* __restrict__ dinv,
                          unsigned short* __restrict__ agg, int N) {
    int lane = threadIdx.x & 63;
    int wave = threadIdx.x >> 6;
    int node = blockIdx.x * 4 + wave;
    if (node >= N) return;
    int c = lane & 15, grp = lane >> 4;

    int st = offs[node];
    int cn = cnt[node];
    float di = dinv[node];

    float4 aC = {0.f, 0.f, 0.f, 0.f}, aD = {0.f, 0.f, 0.f, 0.f};
    for (int e = 0; e < cn; e += 8) {
        int i0 = e + grp, i1 = e + 4 + grp;
        float m0 = (i0 < cn) ? 1.f : 0.f;
        float m1 = (i1 < cn) ? 1.f : 0.f;
        int s0 = csr[st + (i0 < cn ? i0 : cn - 1)];
        int s1 = csr[st + (i1 < cn ? i1 : cn - 1)];
        float w0 = m0 * dinv[s0];
        float w1 = m1 * dinv[s1];
        const unsigned short* p0 = gs + (size_t)s0 * 128 + 4 * c;
        const unsigned short* p1 = gs + (size_t)s1 * 128 + 4 * c;
        ushort4 g0u = *(const ushort4*)p0;
        ushort4 g1u = *(const ushort4*)p1;
        ushort4 t0u = *(const ushort4*)(p0 + 64);
        ushort4 t1u = *(const ushort4*)(p1 + 64);
        aC.x += w0 * bf2f(g0u.x) + w1 * bf2f(g1u.x);
        aC.y += w0 * bf2f(g0u.y) + w1 * bf2f(g1u.y);
        aC.z += w0 * bf2f(g0u.z) + w1 * bf2f(g1u.z);
        aC.w += w0 * bf2f(g0u.w) + w1 * bf2f(g1u.w);
        aD.x += m0 * bf2f(t0u.x) + m1 * bf2f(t1u.x);
        aD.y += m0 * bf2f(t0u.y) + m1 * bf2f(t1u.y);
        aD.z += m0 * bf2f(t0u.z) + m1 * bf2f(t1u.z);
        aD.w += m0 * bf2f(t0u.w) + m1 * bf2f(t1u.w);
    }
    xor_reduce8(aC, aD);

    if (grp == 0) {
        ushort4 su = *(const ushort4*)&gs[(size_t)node * 128 + 4 * c];
        float d2 = di * di;
        ushort4 o;
        o.x = f2bf(di * aC.x + d2 * bf2f(su.x));
        o.y = f2bf(di * aC.y + d2 * bf2f(su.y));
        o.z = f2bf(di * aC.z + d2 * bf2f(su.z));
        o.w = f2bf(di * aC.w + d2 * bf2f(su.w));
        *(ushort4*)&agg[(size_t)node * 128 + 4 * c] = o;
    } else if (grp == 1) {
        float rn = 1.0f / fmaxf((float)cn, 1.0f);
        ushort4 o;
        o.x = f2bf(aD.x * rn); o.y = f2bf(aD.y * rn);
        o.z = f2bf(aD.z * rn); o.w = f2bf(aD.w * rn);
        *(ushort4*)&agg[(size_t)node * 128 + 64 + 4 * c] = o;
    }
}

// Layer-1 GEMMs via MFMA. use_xb selects bf16 or fp32 x source (uniform).
__launch_bounds__(512, 1)
__global__ void k_gemm1(const unsigned short* __restrict__ agg,
                        const unsigned short* __restrict__ xb,
                        const float* __restrict__ xf, int use_xb,
                        const float* __restrict__ W1, const float* __restrict__ b1,
                        const float* __restrict__ Wl1, const float* __restrict__ bl1,
                        const float* __restrict__ Wr1,
                        unsigned short* __restrict__ buf1, int N) {
    alignas(16) __shared__ unsigned short sW[3][4096];
    int t = threadIdx.x;
    for (int i = t; i < 1536; i += 512) {
        int m = i >> 9;
        int rem = i & 511;
        int f = rem >> 6;
        int L = rem & 63;
        int kb = (f >> 2) * 32 + (L >> 4) * 8;
        int o = (f & 3) * 16 + (L & 15);
        const float* Wsrc = (m == 0) ? W1 : (m == 1) ? Wl1 : Wr1;
        unsigned short* dst = &sW[m][f * 512 + L * 8];
        #pragma unroll
        for (int j = 0; j < 8; ++j) dst[j] = f2bf(Wsrc[(kb + j) * 64 + o]);
    }
    __syncthreads();

    int lane = t & 63;
    int wave = t >> 6;
    int quad = lane >> 4;
    int n16 = lane & 15;
    int base = blockIdx.x * 128 + wave * 16;
    if (base >= N) return;

    int nm = base + n16;
    if (nm >= N) nm = N - 1;
    const unsigned short* ar = agg + (size_t)nm * 128;

    {
        short8 a0 = *(const short8*)(ar + quad * 8);
        short8 a1 = *(const short8*)(ar + 32 + quad * 8);
        floatx4 g0 = {0.f, 0.f, 0.f, 0.f}, g1 = g0, g2 = g0, g3 = g0;
        g0 = __builtin_amdgcn_mfma_f32_16x16x32_bf16(a0, *(const short8*)&sW[0][0 * 512 + lane * 8], g0, 0, 0, 0);
        g0 = __builtin_amdgcn_mfma_f32_16x16x32_bf16(a1, *(const short8*)&sW[0][4 * 512 + lane * 8], g0, 0, 0, 0);
        g1 = __builtin_amdgcn_mfma_f32_16x16x32_bf16(a0, *(const short8*)&sW[0][1 * 512 + lane * 8], g1, 0, 0, 0);
        g1 = __builtin_amdgcn_mfma_f32_16x16x32_bf16(a1, *(const short8*)&sW[0][5 * 512 + lane * 8], g1, 0, 0, 0);
        g2 = __builtin_amdgcn_mfma_f32_16x16x32_bf16(a0, *(const short8*)&sW[0][2 * 512 + lane * 8], g2, 0, 0, 0);
        g2 = __builtin_amdgcn_mfma_f32_16x16x32_bf16(a1, *(const short8*)&sW[0][6 * 512 + lane * 8], g2, 0, 0, 0);
        g3 = __builtin_amdgcn_mfma_f32_16x16x32_bf16(a0, *(const short8*)&sW[0][3 * 512 + lane * 8], g3, 0, 0, 0);
        g3 = __builtin_amdgcn_mfma_f32_16x16x32_bf16(a1, *(const short8*)&sW[0][7 * 512 + lane * 8], g3, 0, 0, 0);
        floatx4 gt[4] = {g0, g1, g2, g3};
        #pragma unroll
        for (int nt = 0; nt < 4; ++nt) {
            float bg = b1[nt * 16 + n16];
            #pragma unroll
            for (int r = 0; r < 4; ++r) {
                int node = base + quad * 4 + r;
                if (node < N)
                    buf1[(size_t)node * 128 + nt * 16 + n16] = f2bf(fmaxf(gt[nt][r] + bg, 0.f));
            }
        }
    }

    {
        short8 a0 = *(const short8*)(ar + 64 + quad * 8);
        short8 a1 = *(const short8*)(ar + 96 + quad * 8);
        short8 ax0, ax1;
        if (use_xb) {
            ax0 = *(const short8*)&xb[(size_t)nm * 64 + quad * 8];
            ax1 = *(const short8*)&xb[(size_t)nm * 64 + 32 + quad * 8];
        } else {
            float4 xq0 = *(const float4*)&xf[(size_t)nm * 64 + quad * 8];
            float4 xq1 = *(const float4*)&xf[(size_t)nm * 64 + quad * 8 + 4];
            float4 xq2 = *(const float4*)&xf[(size_t)nm * 64 + 32 + quad * 8];
            float4 xq3 = *(const float4*)&xf[(size_t)nm * 64 + 32 + quad * 8 + 4];
            ax0[0] = (short)f2bf(xq0.x); ax0[1] = (short)f2bf(xq0.y);
            ax0[2] = (short)f2bf(xq0.z); ax0[3] = (short)f2bf(xq0.w);
            ax0[4] = (short)f2bf(xq1.x); ax0[5] = (short)f2bf(xq1.y);
            ax0[6] = (short)f2bf(xq1.z); ax0[7] = (short)f2bf(xq1.w);
            ax1[0] = (short)f2bf(xq2.x); ax1[1] = (short)f2bf(xq2.y);
            ax1[2] = (short)f2bf(xq2.z); ax1[3] = (short)f2bf(xq2.w);
            ax1[4] = (short)f2bf(xq3.x); ax1[5] = (short)f2bf(xq3.y);
            ax1[6] = (short)f2bf(xq3.z); ax1[7] = (short)f2bf(xq3.w);
        }

        floatx4 s0 = {0.f, 0.f, 0.f, 0.f}, s1 = s0, s2 = s0, s3 = s0;
        s0 = __builtin_amdgcn_mfma_f32_16x16x32_bf16(a0, *(const short8*)&sW[1][0 * 512 + lane * 8], s0, 0, 0, 0);
        s0 = __builtin_amdgcn_mfma_f32_16x16x32_bf16(a1, *(const short8*)&sW[1][4 * 512 + lane * 8], s0, 0, 0, 0);
        s0 = __builtin_amdgcn_mfma_f32_16x16x32_bf16(ax0, *(const short8*)&sW[2][0 * 512 + lane * 8], s0, 0, 0, 0);
        s0 = __builtin_amdgcn_mfma_f32_16x16x32_bf16(ax1, *(const short8*)&sW[2][4 * 512 + lane * 8], s0, 0, 0, 0);
        s1 = __builtin_amdgcn_mfma_f32_16x16x32_bf16(a0, *(const short8*)&sW[1][1 * 512 + lane * 8], s1, 0, 0, 0);
        s1 = __builtin_amdgcn_mfma_f32_16x16x32_bf16(a1, *(const short8*)&sW[1][5 * 512 + lane * 8], s1, 0, 0, 0);
        s1 = __builtin_amdgcn_mfma_f32_16x16x32_bf16(ax0, *(const short8*)&sW[2][1 * 512 + lane * 8], s1, 0, 0, 0);
        s1 = __builtin_amdgcn_mfma_f32_16x16x32_bf16(ax1, *(const short8*)&sW[2][5 * 512 + lane * 8], s1, 0, 0, 0);
        s2 = __builtin_amdgcn_mfma_f32_16x16x32_bf16(a0, *(const short8*)&sW[1][2 * 512 + lane * 8], s2, 0, 0, 0);
        s2 = __builtin_amdgcn_mfma_f32_16x16x32_bf16(a1, *(const short8*)&sW[1][6 * 512 + lane * 8], s2, 0, 0, 0);
        s2 = __builtin_amdgcn_mfma_f32_16x16x32_bf16(ax0, *(const short8*)&sW[2][2 * 512 + lane * 8], s2, 0, 0, 0);
        s2 = __builtin_amdgcn_mfma_f32_16x16x32_bf16(ax1, *(const short8*)&sW[2][6 * 512 + lane * 8], s2, 0, 0, 0);
        s3 = __builtin_amdgcn_mfma_f32_16x16x32_bf16(a0, *(const short8*)&sW[1][3 * 512 + lane * 8], s3, 0, 0, 0);
        s3 = __builtin_amdgcn_mfma_f32_16x16x32_bf16(a1, *(const short8*)&sW[1][7 * 512 + lane * 8], s3, 0, 0, 0);
        s3 = __builtin_amdgcn_mfma_f32_16x16x32_bf16(ax0, *(const short8*)&sW[2][3 * 512 + lane * 8], s3, 0, 0, 0);
        s3 = __builtin_amdgcn_mfma_f32_16x16x32_bf16(ax1, *(const short8*)&sW[2][7 * 512 + lane * 8], s3, 0, 0, 0);
        floatx4 stl[4] = {s0, s1, s2, s3};
        #pragma unroll
        for (int nt = 0; nt < 4; ++nt) {
            float bs = bl1[nt * 16 + n16];
            #pragma unroll
            for (int r = 0; r < 4; ++r) {
                int node = base + quad * 4 + r;
                if (node < N)
                    buf1[(size_t)node * 128 + 64 + nt * 16 + n16] = f2bf(fmaxf(stl[nt][r] + bs, 0.f));
            }
        }
    }
}

// Layer-2 GEMMs + LN + concat-proj via MFMA (proven in R8).
__launch_bounds__(512, 1)
__global__ void k_gemm2(const unsigned short* __restrict__ agg,
                        const unsigned short* __restrict__ buf1,
                        const float* __restrict__ W2, const float* __restrict__ b2,
                        const float* __restrict__ Wl2, const float* __restrict__ bl2,
                        const float* __restrict__ Wr2,
                        const float* __restrict__ lngG, const float* __restrict__ lnbG,
                        const float* __restrict__ lngS, const float* __restrict__ lnbS,
                        const float* __restrict__ Pw, const float* __restrict__ Pb,
                        float* __restrict__ out, int N) {
    alignas(16) __shared__ unsigned short sW[3][4096];
    alignas(16) __shared__ unsigned short sP[8192];
    alignas(16) __shared__ unsigned short sT[8][16 * 132];
    int t = threadIdx.x;
    for (int i = t; i < 1536; i += 512) {
        int m = i >> 9;
        int rem = i & 511;
        int f = rem >> 6;
        int L = rem & 63;
        int kb = (f >> 2) * 32 + (L >> 4) * 8;
        int o = (f & 3) * 16 + (L & 15);
        const float* Wsrc = (m == 0) ? W2 : (m == 1) ? Wl2 : Wr2;
        unsigned short* dst = &sW[m][f * 512 + L * 8];
        #pragma unroll
        for (int j = 0; j < 8; ++j) dst[j] = f2bf(Wsrc[(kb + j) * 64 + o]);
    }
    for (int i = t; i < 1024; i += 512) {
        int f = i >> 6;
        int L = i & 63;
        int kb = (f >> 2) * 32 + (L >> 4) * 8;
        int o = (f & 3) * 16 + (L & 15);
        unsigned short* dst = &sP[f * 512 + L * 8];
        #pragma unroll
        for (int j = 0; j < 8; ++j) dst[j] = f2bf(Pw[(kb + j) * 64 + o]);
    }
    __syncthreads();

    int lane = t & 63;
    int wave = t >> 6;
    int quad = lane >> 4;
    int n16 = lane & 15;
    int base = blockIdx.x * 128 + wave * 16;
    if (base >= N) return;
    int nm = base + n16;
    if (nm >= N) nm = N - 1;
    const unsigned short* ar = agg + (size_t)nm * 128;
    const unsigned short* br = buf1 + (size_t)nm * 128;
    unsigned short* tw = &sT[wave][0];

    {
        short8 a0 = *(const short8*)(ar + quad * 8);
        short8 a1 = *(const short8*)(ar + 32 + quad * 8);
        floatx4 c0 = {0.f, 0.f, 0.f, 0.f}, c1 = c0, c2 = c0, c3 = c0;
        c0 = __builtin_amdgcn_mfma_f32_16x16x32_bf16(a0, *(const short8*)&sW[0][0 * 512 + lane * 8], c0, 0, 0, 0);
        c0 = __builtin_amdgcn_mfma_f32_16x16x32_bf16(a1, *(const short8*)&sW[0][4 * 512 + lane * 8], c0, 0, 0, 0);
        c1 = __builtin_amdgcn_mfma_f32_16x16x32_bf16(a0, *(const short8*)&sW[0][1 * 512 + lane * 8], c1, 0, 0, 0);
        c1 = __builtin_amdgcn_mfma_f32_16x16x32_bf16(a1, *(const short8*)&sW[0][5 * 512 + lane * 8], c1, 0, 0, 0);
        c2 = __builtin_amdgcn_mfma_f32_16x16x32_bf16(a0, *(const short8*)&sW[0][2 * 512 + lane * 8], c2, 0, 0, 0);
        c2 = __builtin_amdgcn_mfma_f32_16x16x32_bf16(a1, *(const short8*)&sW[0][6 * 512 + lane * 8], c2, 0, 0, 0);
        c3 = __builtin_amdgcn_mfma_f32_16x16x32_bf16(a0, *(const short8*)&sW[0][3 * 512 + lane * 8], c3, 0, 0, 0);
        c3 = __builtin_amdgcn_mfma_f32_16x16x32_bf16(a1, *(const short8*)&sW[0][7 * 512 + lane * 8], c3, 0, 0, 0);

        float bv0 = b2[n16], bv1 = b2[16 + n16], bv2 = b2[32 + n16], bv3 = b2[48 + n16];
        float gv0 = lngG[n16], gv1 = lngG[16 + n16], gv2 = lngG[32 + n16], gv3 = lngG[48 + n16];
        float ev0 = lnbG[n16], ev1 = lnbG[16 + n16], ev2 = lnbG[32 + n16], ev3 = lnbG[48 + n16];
        #pragma unroll
        for (int r = 0; r < 4; ++r) {
            float z0 = c0[r] + bv0, z1 = c1[r] + bv1, z2 = c2[r] + bv2, z3 = c3[r] + bv3;
            float s = red16(z0 + z1 + z2 + z3);
            float q = red16(z0 * z0 + z1 * z1 + z2 * z2 + z3 * z3);
            float mu = s * (1.0f / 64.0f);
            float var = fmaxf(q * (1.0f / 64.0f) - mu * mu, 0.0f);
            float rs = rsqrtf(var + 1e-5f);
            unsigned short* row = tw + (quad * 4 + r) * 132;
            row[n16]      = f2bf((z0 - mu) * rs * gv0 + ev0);
            row[16 + n16] = f2bf((z1 - mu) * rs * gv1 + ev1);
            row[32 + n16] = f2bf((z2 - mu) * rs * gv2 + ev2);
            row[48 + n16] = f2bf((z3 - mu) * rs * gv3 + ev3);
        }
    }

    {
        short8 a0 = *(const short8*)(ar + 64 + quad * 8);
        short8 a1 = *(const short8*)(ar + 96 + quad * 8);
        short8 v0 = *(const short8*)(br + 64 + quad * 8);
        short8 v1 = *(const short8*)(br + 96 + quad * 8);
        floatx4 c0 = {0.f, 0.f, 0.f, 0.f}, c1 = c0, c2 = c0, c3 = c0;
        c0 = __builtin_amdgcn_mfma_f32_16x16x32_bf16(a0, *(const short8*)&sW[1][0 * 512 + lane * 8], c0, 0, 0, 0);
        c0 = __builtin_amdgcn_mfma_f32_16x16x32_bf16(a1, *(const short8*)&sW[1][4 * 512 + lane * 8], c0, 0, 0, 0);
        c0 = __builtin_amdgcn_mfma_f32_16x16x32_bf16(v0, *(const short8*)&sW[2][0 * 512 + lane * 8], c0, 0, 0, 0);
        c0 = __builtin_amdgcn_mfma_f32_16x16x32_bf16(v1, *(const short8*)&sW[2][4 * 512 + lane * 8], c0, 0, 0, 0);
        c1 = __builtin_amdgcn_mfma_f32_16x16x32_bf16(a0, *(const short8*)&sW[1][1 * 512 + lane * 8], c1, 0, 0, 0);
        c1 = __builtin_amdgcn_mfma_f32_16x16x32_bf16(a1, *(const short8*)&sW[1][5 * 512 + lane * 8], c1, 0, 0, 0);
        c1 = __builtin_amdgcn_mfma_f32_16x16x32_bf16(v0, *(const short8*)&sW[2][1 * 512 + lane * 8], c1, 0, 0, 0);
        c1 = __builtin_amdgcn_mfma_f32_16x16x32_bf16(v1, *(const short8*)&sW[2][5 * 512 + lane * 8], c1, 0, 0, 0);
        c2 = __builtin_amdgcn_mfma_f32_16x16x32_bf16(a0, *(const short8*)&sW[1][2 * 512 + lane * 8], c2, 0, 0, 0);
        c2 = __builtin_amdgcn_mfma_f32_16x16x32_bf16(a1, *(const short8*)&sW[1][6 * 512 + lane * 8], c2, 0, 0, 0);
        c2 = __builtin_amdgcn_mfma_f32_16x16x32_bf16(v0, *(const short8*)&sW[2][2 * 512 + lane * 8], c2, 0, 0, 0);
        c2 = __builtin_amdgcn_mfma_f32_16x16x32_bf16(v1, *(const short8*)&sW[2][6 * 512 + lane * 8], c2, 0, 0, 0);
        c3 = __builtin_amdgcn_mfma_f32_16x16x32_bf16(a0, *(const short8*)&sW[1][3 * 512 + lane * 8], c3, 0, 0, 0);
        c3 = __builtin_amdgcn_mfma_f32_16x16x32_bf16(a1, *(const short8*)&sW[1][7 * 512 + lane * 8], c3, 0, 0, 0);
        c3 = __builtin_amdgcn_mfma_f32_16x16x32_bf16(v0, *(const short8*)&sW[2][3 * 512 + lane * 8], c3, 0, 0, 0);
        c3 = __builtin_amdgcn_mfma_f32_16x16x32_bf16(v1, *(const short8*)&sW[2][7 * 512 + lane * 8], c3, 0, 0, 0);

        float bv0 = bl2[n16], bv1 = bl2[16 + n16], bv2 = bl2[32 + n16], bv3 = bl2[48 + n16];
        float gv0 = lngS[n16], gv1 = lngS[16 + n16], gv2 = lngS[32 + n16], gv3 = lngS[48 + n16];
        float ev0 = lnbS[n16], ev1 = lnbS[16 + n16], ev2 = lnbS[32 + n16], ev3 = lnbS[48 + n16];
        #pragma unroll
        for (int r = 0; r < 4; ++r) {
            float z0 = c0[r] + bv0, z1 = c1[r] + bv1, z2 = c2[r] + bv2, z3 = c3[r] + bv3;
            float s = red16(z0 + z1 + z2 + z3);
            float q = red16(z0 * z0 + z1 * z1 + z2 * z2 + z3 * z3);
            float mu = s * (1.0f / 64.0f);
            float var = fmaxf(q * (1.0f / 64.0f) - mu * mu, 0.0f);
            float rs = rsqrtf(var + 1e-5f);
            unsigned short* row = tw + (quad * 4 + r) * 132 + 64;
            row[n16]      = f2bf((z0 - mu) * rs * gv0 + ev0);
            row[16 + n16] = f2bf((z1 - mu) * rs * gv1 + ev1);
            row[32 + n16] = f2bf((z2 - mu) * rs * gv2 + ev2);
            row[48 + n16] = f2bf((z3 - mu) * rs * gv3 + ev3);
        }
    }

    floatx4 o0 = {0.f, 0.f, 0.f, 0.f}, o1 = o0, o2 = o0, o3 = o0;
    #pragma unroll
    for (int ks = 0; ks < 4; ++ks) {
        const unsigned short* ap = tw + n16 * 132 + ks * 32 + quad * 8;
        short4v lo = *(const short4v*)ap;
        short4v hi = *(const short4v*)(ap + 4);
        short8 af;
        af[0] = lo[0]; af[1] = lo[1]; af[2] = lo[2]; af[3] = lo[3];
        af[4] = hi[0]; af[5] = hi[1]; af[6] = hi[2]; af[7] = hi[3];
        o0 = __builtin_amdgcn_mfma_f32_16x16x32_bf16(af, *(const short8*)&sP[(ks * 4 + 0) * 512 + lane * 8], o0, 0, 0, 0);
        o1 = __builtin_amdgcn_mfma_f32_16x16x32_bf16(af, *(const short8*)&sP[(ks * 4 + 1) * 512 + lane * 8], o1, 0, 0, 0);
        o2 = __builtin_amdgcn_mfma_f32_16x16x32_bf16(af, *(const short8*)&sP[(ks * 4 + 2) * 512 + lane * 8], o2, 0, 0, 0);
        o3 = __builtin_amdgcn_mfma_f32_16x16x32_bf16(af, *(const short8*)&sP[(ks * 4 + 3) * 512 + lane * 8], o3, 0, 0, 0);
    }
    float p0 = Pb[n16], p1 = Pb[16 + n16], p2 = Pb[32 + n16], p3 = Pb[48 + n16];
    floatx4 ot[4] = {o0, o1, o2, o3};
    float pv[4] = {p0, p1, p2, p3};
    #pragma unroll
    for (int nt = 0; nt < 4; ++nt) {
        #pragma unroll
        for (int r = 0; r < 4; ++r) {
            int node = base + quad * 4 + r;
            if (node < N) out[(size_t)node * 64 + nt * 16 + n16] = ot[nt][r] + pv[nt];
        }
    }
}

extern "C" void kernel_launch(void* const* d_in, const int* in_sizes, int n_in,
                              void* d_out, int out_size, void* d_ws, size_t ws_size,
                              hipStream_t stream) {
    const float* x        = (const float*)d_in[0];
    const int*   ei       = (const int*)d_in[1];
    const float* gcn_w1   = (const float*)d_in[2];
    const float* gcn_b1   = (const float*)d_in[3];
    const float* gcn_w2   = (const float*)d_in[4];
    const float* gcn_b2   = (const float*)d_in[5];
    const float* sage_wl1 = (const float*)d_in[6];
    const float* sage_bl1 = (const float*)d_in[7];
    const float* sage_wr1 = (const float*)d_in[8];
    const float* sage_wl2 = (const float*)d_in[9];
    const float* sage_bl2 = (const float*)d_in[10];
    const float* sage_wr2 = (const float*)d_in[11];
    const float* gcn_ln_g = (const float*)d_in[12];
    const float* gcn_ln_b = (const float*)d_in[13];
    const float* sage_ln_g = (const float*)d_in[14];
    const float* sage_ln_b = (const float*)d_in[15];
    const float* proj_w   = (const float*)d_in[16];
    const float* proj_b   = (const float*)d_in[17];
    float* out = (float*)d_out;

    const int N = in_sizes[0] / 64;
    const int E = in_sizes[1] / 2;
    const int B = (N + SCAN_CHUNK - 1) / SCAN_CHUNK;

    char* w = (char*)d_ws;
    size_t off = 0;
    auto alloc = [&](size_t bytes) -> void* {
        void* p = w + off;
        off = (off + bytes + 255) & ~(size_t)255;
        return p;
    };
    int*            cnt       = (int*)alloc((size_t)N * 4);
    int*            offs      = (int*)alloc((size_t)(N + 1) * 4);
    float*          dinv      = (float*)alloc((size_t)N * 4);
    int*            blockSums = (int*)alloc((size_t)(B + 1) * 4);
    int*            csr       = (int*)alloc((size_t)(E + N + 64) * 4);
    unsigned int*   cnt8      = (unsigned int*)alloc((size_t)8 * N * 4);
    int*            boff8     = (int*)alloc((size_t)8 * N * 4);
    unsigned short* agg       = (unsigned short*)alloc((size_t)N * 128 * 2);  // also aliases rank (dead before gather1)
    unsigned short* buf1      = (unsigned short*)alloc((size_t)N * 128 * 2);
    size_t off_nonew = off;
    unsigned int*   pk        = (unsigned int*)alloc((size_t)(E + N + 64) * 4);
    unsigned short* xb        = (unsigned short*)alloc((size_t)N * 64 * 2);
    int use_new = (off <= ws_size) ? 1 : 0;
    if (!use_new) off = off_nonew;
    int* rank = (int*)agg;  // E*4 = 5MB <= 25.6MB agg region
    (void)n_in; (void)out_size;

    hipMemsetAsync(cnt8, 0, (size_t)8 * N * 4, stream);

    int e8Blocks = ((E + 7) / 8 + 255) / 256;
    int x8Blocks = ((N * 64 + 7) / 8 + 255) / 256;
    int cntBlocks = use_new ? max(e8Blocks, x8Blocks) : e8Blocks;
    int fillBlocks = use_new ? max(e8Blocks, (N + 255) / 256) : e8Blocks;
    k_count<<<cntBlocks, 256, 0, stream>>>(ei, E, cnt8, N, rank, x, xb, N * 64, use_new);
    k_scan_reduce<<<B, 256, 0, stream>>>(cnt8, N, blockSums);
    k_scan_spine<<<1, 64, 0, stream>>>(blockSums, B);
    k_scan_write<<<B, 256, 0, stream>>>(cnt8, N, blockSums, offs, cnt, dinv, boff8);
    k_fill<<<fillBlocks, 256, 0, stream>>>(ei, E, offs, rank, cnt, boff8, N, dinv, csr, pk, use_new);

    if (use_new) {
        k_gatherM<64><<<(N + 63) / 64, 256, 0, stream>>>(xb, csr, pk, offs, cnt, agg, N);
        k_gemm1<<<(N + 127) / 128, 512, 0, stream>>>(agg, xb, x, 1, gcn_w1, gcn_b1,
                                                     sage_wl1, sage_bl1, sage_wr1, buf1, N);
        k_gatherM<128><<<(N + 63) / 64, 256, 0, stream>>>(buf1, csr, pk, offs, cnt, agg, N);
    } else {
        k_gather1_f32<<<(N + 3) / 4, 256, 0, stream>>>(x, csr, offs, cnt, dinv, agg, N);
        k_gemm1<<<(N + 127) / 128, 512, 0, stream>>>(agg, xb, x, 0, gcn_w1, gcn_b1,
                                                     sage_wl1, sage_bl1, sage_wr1, buf1, N);
        k_gather2<<<(N + 3) / 4, 256, 0, stream>>>(buf1, csr, offs, cnt, dinv, agg, N);
    }
    k_gemm2<<<(N + 127) / 128, 512, 0, stream>>>(agg, buf1, gcn_w2, gcn_b2,
                                                 sage_wl2, sage_bl2, sage_wr2,
                                                 gcn_ln_g, gcn_ln_b, sage_ln_g, sage_ln_b,
                                                 proj_w, proj_b, out, N);
}

// Round 9
// 333.168 us; speedup vs baseline: 1.0931x; 1.0931x over previous
//
#include <hip/hip_runtime.h>

// N=100000 nodes, E=1250000 edges, all dims 64.
// R18: R17 (atomic-free group-CSR preprocessing) failed correctness with a
// non-deterministic error; gather/GEMM were identical to passing R14, so the
// bug is in preprocessing. The three NOVEL mechanisms (shfl_up wave-scan
// bases, ballot degree recovery, shfl-from-divergent-branch weights) are
// replaced with trivially-verifiable equivalents:
//  - k_bases: serial per-group thread (coalesced across g per block-iter).
//  - k_degself: per-wave LDS counters (same proven mechanism as k_scatter),
//    proper barriers, no early return before __syncthreads.
//  - k_weights: direct dinv[g*16+d15] load, no cross-lane ops.
// hist/colsum/scans/scatter and all gather/GEMM kernels unchanged from R17.

#define SCAN_CHUNK 2048
#define NB 256        // histogram/scatter blocks
#define GMAX 8192     // max groups (N <= 131072)

typedef __attribute__((ext_vector_type(8))) short short8;   // 8 bf16 = 4 VGPRs
typedef __attribute__((ext_vector_type(4))) short short4v;  // 4 bf16 = 2 VGPRs
typedef __attribute__((ext_vector_type(4))) float floatx4;  // MFMA C/D

__device__ __forceinline__ unsigned short f2bf(float f) {
    unsigned int u = __float_as_uint(f);
    unsigned int r = u + 0x7FFFu + ((u >> 16) & 1u);  // round-to-nearest-even
    return (unsigned short)(r >> 16);
}
__device__ __forceinline__ float bf2f(unsigned short h) {
    return __uint_as_float(((unsigned int)h) << 16);
}

__device__ __forceinline__ unsigned lds_addr(const void* p) {
    return (unsigned)(unsigned long long)(__attribute__((address_space(3))) const char*)p;
}

__device__ __forceinline__ short8 cat44(short4v lo, short4v hi) {
    short8 r;
    r[0] = lo[0]; r[1] = lo[1]; r[2] = lo[2]; r[3] = lo[3];
    r[4] = hi[0]; r[5] = hi[1]; r[6] = hi[2]; r[7] = hi[3];
    return r;
}

// Read 4 B-frags (col-tiles CTB..CTB+3) for this lane's k-group via HW transpose.
// LDS holds 32xROWSH bf16 tile subtiled [k/4][f/16][4][16]; subtile s at byte s*128.
// a0 = wb_base + (q*2*NF)*128 + (lane&15)*8.
template<int NF, int CTB>
__device__ __forceinline__ void tr_read4(unsigned a0, short8 bf[4]) {
    short4v l0, h0, l1, h1, l2, h2, l3, h3;
    asm volatile(
        "ds_read_b64_tr_b16 %0, %8 offset:%9\n\t"
        "ds_read_b64_tr_b16 %1, %8 offset:%10\n\t"
        "ds_read_b64_tr_b16 %2, %8 offset:%11\n\t"
        "ds_read_b64_tr_b16 %3, %8 offset:%12\n\t"
        "ds_read_b64_tr_b16 %4, %8 offset:%13\n\t"
        "ds_read_b64_tr_b16 %5, %8 offset:%14\n\t"
        "ds_read_b64_tr_b16 %6, %8 offset:%15\n\t"
        "ds_read_b64_tr_b16 %7, %8 offset:%16\n\t"
        "s_waitcnt lgkmcnt(0)"
        : "=&v"(l0), "=&v"(h0), "=&v"(l1), "=&v"(h1),
          "=&v"(l2), "=&v"(h2), "=&v"(l3), "=&v"(h3)
        : "v"(a0),
          "i"((0 * NF + CTB + 0) * 128), "i"((1 * NF + CTB + 0) * 128),
          "i"((0 * NF + CTB + 1) * 128), "i"((1 * NF + CTB + 1) * 128),
          "i"((0 * NF + CTB + 2) * 128), "i"((1 * NF + CTB + 2) * 128),
          "i"((0 * NF + CTB + 3) * 128), "i"((1 * NF + CTB + 3) * 128)
        : "memory");
    bf[0] = cat44(l0, h0);
    bf[1] = cat44(l1, h1);
    bf[2] = cat44(l2, h2);
    bf[3] = cat44(l3, h3);
}

// per-block LDS group histogram (no global atomics); fused x->bf16
__global__ void k_hist(const int* __restrict__ ei, int E, int G,
                       unsigned* __restrict__ counts,
                       const float* __restrict__ x, unsigned short* __restrict__ xb,
                       int xtotal) {
    __shared__ unsigned hist[GMAX];
    int t = threadIdx.x, b = blockIdx.x;
    for (int i = t; i < G; i += 256) hist[i] = 0;
    __syncthreads();
    int ec = (E + NB - 1) / NB;
    int lo = b * ec, hi = min(lo + ec, E);
    for (int idx = lo + t; idx < hi; idx += 256)
        atomicAdd(&hist[ei[E + idx] >> 4], 1u);
    __syncthreads();
    for (int i = t; i < G; i += 256) counts[(size_t)b * G + i] = hist[i];
    int nv = xtotal >> 3;
    for (int v = b * 256 + t; v < nv; v += NB * 256) {
        int e = v * 8;
        float4 a = *(const float4*)&x[e];
        float4 c = *(const float4*)&x[e + 4];
        short8 o;
        o[0] = (short)f2bf(a.x); o[1] = (short)f2bf(a.y);
        o[2] = (short)f2bf(a.z); o[3] = (short)f2bf(a.w);
        o[4] = (short)f2bf(c.x); o[5] = (short)f2bf(c.y);
        o[6] = (short)f2bf(c.z); o[7] = (short)f2bf(c.w);
        *(short8*)&xb[e] = o;
    }
}

// cnt16[g] = sum over blocks of counts[b][g] (coalesced across g)
__global__ void k_colsum(const unsigned* __restrict__ counts, int G,
                         int* __restrict__ cnt16) {
    int g = blockIdx.x * 256 + threadIdx.x;
    if (g < G) {
        int tot = 0;
        for (int b = 0; b < NB; ++b) tot += (int)counts[(size_t)b * G + g];
        cnt16[g] = tot;
    }
}

// scan over (cnt16[g] + 16): 16 self slots per group
__global__ void k_gr(const int* __restrict__ cnt16, int G, int* __restrict__ blockSums) {
    __shared__ int lds[256];
    int base = blockIdx.x * SCAN_CHUNK;
    int t = threadIdx.x;
    int s = 0;
    for (int j = 0; j < 8; ++j) {
        int idx = base + t * 8 + j;
        if (idx < G) s += cnt16[idx] + 16;
    }
    lds[t] = s;
    __syncthreads();
    for (int d = 128; d > 0; d >>= 1) {
        if (t < d) lds[t] += lds[t + d];
        __syncthreads();
    }
    if (t == 0) blockSums[blockIdx.x] = lds[0];
}

__global__ void k_scan_spine(int* __restrict__ blockSums, int B) {
    if (threadIdx.x == 0 && blockIdx.x == 0) {
        int run = 0;
        for (int b = 0; b < B; ++b) { int v = blockSums[b]; blockSums[b] = run; run += v; }
    }
}

__global__ void k_gw(const int* __restrict__ cnt16, int G,
                     const int* __restrict__ blockSums, int* __restrict__ offs16) {
    __shared__ int lds[256];
    int base = blockIdx.x * SCAN_CHUNK;
    int t = threadIdx.x;
    int v[8];
    int s = 0;
    for (int j = 0; j < 8; ++j) {
        int idx = base + t * 8 + j;
        v[j] = (idx < G) ? cnt16[idx] : 0;
        s += (idx < G) ? v[j] + 16 : 0;
    }
    lds[t] = s;
    __syncthreads();
    for (int d = 1; d < 256; d <<= 1) {
        int x = (t >= d) ? lds[t - d] : 0;
        __syncthreads();
        lds[t] += x;
        __syncthreads();
    }
    int excl = (t == 0) ? 0 : lds[t - 1];
    int run = blockSums[blockIdx.x] + excl;
    for (int j = 0; j < 8; ++j) {
        int idx = base + t * 8 + j;
        if (idx < G) {
            offs16[idx] = run;
            run += v[j] + 16;
            if (idx == G - 1) offs16[G] = run;
        }
    }
}

// counts[b][g] -> absolute base (in place): serial per-group thread.
// For fixed b, adjacent threads touch adjacent g -> fully coalesced.
__global__ void k_bases(unsigned* __restrict__ counts, int G,
                        const int* __restrict__ offs16) {
    int g = blockIdx.x * 256 + threadIdx.x;
    if (g >= G) return;
    unsigned run = (unsigned)offs16[g];
    for (int b = 0; b < NB; ++b) {
        unsigned v = counts[(size_t)b * G + g];
        counts[(size_t)b * G + g] = run;
        run += v;
    }
}

// scatter edges into group-bucketed CSR via LDS cursors (no global atomics)
__global__ void k_scatter(const int* __restrict__ ei, int E, int G,
                          const unsigned* __restrict__ counts,
                          int* __restrict__ csr, unsigned* __restrict__ pk) {
    __shared__ unsigned cur[GMAX];
    int t = threadIdx.x, b = blockIdx.x;
    for (int i = t; i < G; i += 256) cur[i] = counts[(size_t)b * G + i];
    __syncthreads();
    int ec = (E + NB - 1) / NB;
    int lo = b * ec, hi = min(lo + ec, E);
    for (int idx = lo + t; idx < hi; idx += 256) {
        int s = ei[idx];
        int d = ei[E + idx];
        unsigned pos = atomicAdd(&cur[d >> 4], 1u);  // LDS atomic
        csr[pos] = s;
        pk[pos] = (unsigned)(d & 15) << 16;
    }
}

// per-node degree via per-wave LDS counters (proven LDS-atomic mechanism);
// writes cnt/dinv and the 16 self slots (weight di^2, bit20 = SAGE-exclude).
__global__ void k_degself(const int* __restrict__ offs16, int G, int N,
                          int* __restrict__ cnt, float* __restrict__ dinv,
                          int* __restrict__ csr, unsigned* __restrict__ pk) {
    __shared__ int wcnt[4][16];
    int lane = threadIdx.x & 63;
    int wv = threadIdx.x >> 6;
    int g = blockIdx.x * 4 + wv;
    bool act = (g < G);
    if (lane < 16) wcnt[wv][lane] = 0;
    __syncthreads();
    if (act) {
        int lo = offs16[g];
        int rh = offs16[g + 1] - 16;
        for (int idx = lo + lane; idx < rh; idx += 64) {
            int d15 = (int)((pk[idx] >> 16) & 15u);
            atomicAdd(&wcnt[wv][d15], 1);
        }
    }
    __syncthreads();
    if (act && lane < 16) {
        int rh = offs16[g + 1] - 16;
        int deg = wcnt[wv][lane];
        int node = g * 16 + lane;
        int slot = rh + lane;
        if (node < N) {
            cnt[node] = deg;
            float di = rsqrtf((float)deg + 1.0f);
            dinv[node] = di;
            csr[slot] = node;
            pk[slot] = ((unsigned)lane << 16) | (1u << 20) | f2bf(di * di);
        } else {
            csr[slot] = 0;
            pk[slot] = ((unsigned)lane << 16) | (1u << 20);  // w=0, excluded
        }
    }
}

// fill pk weights: bf16(dinv[src] * dinv[dst]); dst = 16g + d15 (direct load)
__global__ void k_weights(const int* __restrict__ csr, const int* __restrict__ offs16,
                          int G, int N, const float* __restrict__ dinv,
                          unsigned* __restrict__ pk) {
    int lane = threadIdx.x & 63;
    int g = blockIdx.x * 4 + (threadIdx.x >> 6);
    if (g >= G) return;
    int lo = offs16[g];
    int rh = offs16[g + 1] - 16;
    for (int idx = lo + lane; idx < rh; idx += 64) {
        unsigned u = pk[idx];
        int s = csr[idx];
        int dst = g * 16 + (int)((u >> 16) & 15u);
        pk[idx] = u | f2bf(dinv[s] * dinv[dst]);
    }
}

// ===================== MFMA SpMM gather (serial, proven R10 structure) ========
// One wave per 16-node group; 4 waves/block; no barriers. Group's edges incl.
// self slots contiguous in [offs16[g], offs16[g+1]). Per 32-edge chunk:
// reg-stage 32 src rows -> conflict-free ds_write, A-frags from resident meta
// regs via shfl, tr_read + 8 MFMAs.
template<int ROWSH>
__launch_bounds__(256)
__global__ void k_gatherM(const unsigned short* __restrict__ feat,
                          const int* __restrict__ csr,
                          const unsigned int* __restrict__ pk,
                          const int* __restrict__ offs16, const int* __restrict__ cnt,
                          unsigned short* __restrict__ agg, int N) {
    constexpr int NF = ROWSH / 16;      // f-subtiles per edge row (4 or 8)
    constexpr int LPR = ROWSH / 8;      // lanes per staged row
    constexpr int EPP = 64 / LPR;       // edges per staging pass
    constexpr int PASSES = 32 / EPP;    // passes per 32-edge chunk (4 or 8)

    __shared__ unsigned short sbuf[4][32 * ROWSH];

    const int lane = threadIdx.x & 63;
    const int wv = threadIdx.x >> 6;
    const int base = blockIdx.x * 64 + wv * 16;
    if (base >= N) return;

    const int q = lane >> 4;
    const int d16 = lane & 15;

    // conflict-free staging map: lane L holds the 16B that belongs at byte
    // p*1024 + 16L of the subtiled LDS image (bijection per 1024B pass block).
    const int parity = lane & 1;
    const int ei_low = (lane >> 1) & 3;
    const int sf_sub = (lane >> 3) & (NF - 1);
    const int ei_high = (NF == 8) ? 0 : (lane >> 5);
    const int eid = ei_high * 4 + ei_low;
    const int sf = sf_sub * 16 + parity * 8;

    const int grp = base >> 4;
    const int elo = offs16[grp];
    const int ehi = offs16[grp + 1];
    const int emax = ehi - 1;
    const int nch = (ehi - elo + 31) >> 5;

    // ---- resident meta: 4 windows of 64 edges (covers 8 chunks = 256 edges) ----
    int cM0, cM1, cM2, cM3;
    unsigned pM0, pM1, pM2, pM3;
    {
        int i0 = elo + lane;
        int i1 = i0 + 64, i2 = i0 + 128, i3 = i0 + 192;
        cM0 = csr[i0 <= emax ? i0 : emax];
        cM1 = csr[i1 <= emax ? i1 : emax];
        cM2 = csr[i2 <= emax ? i2 : emax];
        cM3 = csr[i3 <= emax ? i3 : emax];
        unsigned t0 = pk[i0 <= emax ? i0 : emax];
        unsigned t1 = pk[i1 <= emax ? i1 : emax];
        unsigned t2 = pk[i2 <= emax ? i2 : emax];
        unsigned t3 = pk[i3 <= emax ? i3 : emax];
        pM0 = (i0 < ehi) ? t0 : 0x00100000u;
        pM1 = (i1 < ehi) ? t1 : 0x00100000u;
        pM2 = (i2 < ehi) ? t2 : 0x00100000u;
        pM3 = (i3 < ehi) ? t3 : 0x00100000u;
    }

    floatx4 accg[4], accs[4];
#pragma unroll
    for (int i = 0; i < 4; ++i) {
        accg[i] = floatx4{0.f, 0.f, 0.f, 0.f};
        accs[i] = floatx4{0.f, 0.f, 0.f, 0.f};
    }

    unsigned short* wb = &sbuf[wv][0];
    const unsigned a0 = lds_addr(wb) + (unsigned)(q * 2 * NF) * 128u + (unsigned)d16 * 8u;

    for (int c = 0; c < nch; ++c) {
        // ---- meta for chunk c (resident regs; rare dynamic path >256 edges) ----
        int cv; unsigned pv; int wofs;
        int rc = c >> 1;
        if (rc < 4) {
            wofs = (c & 1) << 5;
            cv = (rc == 0) ? cM0 : (rc == 1) ? cM1 : (rc == 2) ? cM2 : cM3;
            pv = (rc == 0) ? pM0 : (rc == 1) ? pM1 : (rc == 2) ? pM2 : pM3;
        } else {
            int idx = elo + (c << 5) + lane;
            int idc = idx <= emax ? idx : emax;
            cv = csr[idc];
            unsigned t = pk[idc];
            pv = (idx < ehi) ? t : 0x00100000u;
            wofs = 0;
        }

        // ---- issue row loads (addresses from resident regs, no meta loads) ----
        short8 stg[PASSES];
#pragma unroll
        for (int p = 0; p < PASSES; ++p) {
            int src = __shfl(cv, wofs + p * EPP + eid, 64);
            stg[p] = *(const short8*)&feat[(size_t)src * ROWSH + sf];
        }

        // ---- A-frags (register-only; overlaps load latency) ----
        short8 aG, aS;
#pragma unroll
        for (int j = 0; j < 8; ++j) {
            unsigned u = (unsigned)__shfl((int)pv, wofs + q * 8 + j, 64);
            unsigned hi = u >> 16;
            bool match = (int)(hi & 15u) == d16;
            aG[j] = match ? (short)(u & 0xFFFFu) : (short)0;
            aS[j] = (match && !(hi & 16u)) ? (short)0x3F80 : (short)0;
        }

        // ---- conflict-free ds_write (compiler inserts vmcnt waits for stg) ----
#pragma unroll
        for (int p = 0; p < PASSES; ++p)
            *(short8*)&wb[p * 512 + lane * 8] = stg[p];
        asm volatile("s_waitcnt lgkmcnt(0)" ::: "memory");
        __builtin_amdgcn_sched_barrier(0);

        // ---- tr_read + MFMA ----
        short8 bG[4];
        tr_read4<NF, 0>(a0, bG);
#pragma unroll
        for (int ct = 0; ct < 4; ++ct)
            accg[ct] = __builtin_amdgcn_mfma_f32_16x16x32_bf16(aG, bG[ct], accg[ct], 0, 0, 0);
        if constexpr (NF == 8) {
            short8 bS[4];
            tr_read4<NF, 4>(a0, bS);
#pragma unroll
            for (int ct = 0; ct < 4; ++ct)
                accs[ct] = __builtin_amdgcn_mfma_f32_16x16x32_bf16(aS, bS[ct], accs[ct], 0, 0, 0);
        } else {
#pragma unroll
            for (int ct = 0; ct < 4; ++ct)
                accs[ct] = __builtin_amdgcn_mfma_f32_16x16x32_bf16(aS, bG[ct], accs[ct], 0, 0, 0);
        }
    }

    // ---- epilogue: C/D layout row=(q*4+r), col=d16 ----
#pragma unroll
    for (int r = 0; r < 4; ++r) {
        int node = base + q * 4 + r;
        if (node < N) {
            float rn = 1.0f / fmaxf((float)cnt[node], 1.0f);
#pragma unroll
            for (int ct = 0; ct < 4; ++ct) {
                agg[(size_t)node * 128 + ct * 16 + d16]      = f2bf(accg[ct][r]);
                agg[(size_t)node * 128 + 64 + ct * 16 + d16] = f2bf(accs[ct][r] * rn);
            }
        }
    }
}

__device__ __forceinline__ float red16(float v) {
    v += __shfl_xor(v, 1, 64);
    v += __shfl_xor(v, 2, 64);
    v += __shfl_xor(v, 4, 64);
    v += __shfl_xor(v, 8, 64);
    return v;
}

// Layer-1 GEMMs via MFMA.
__launch_bounds__(512, 1)
__global__ void k_gemm1(const unsigned short* __restrict__ agg,
                        const unsigned short* __restrict__ xb,
                        const float* __restrict__ W1, const float* __restrict__ b1,
                        const float* __restrict__ Wl1, const float* __restrict__ bl1,
                        const float* __restrict__ Wr1,
                        unsigned short* __restrict__ buf1, int N) {
    alignas(16) __shared__ unsigned short sW[3][4096];
    int t = threadIdx.x;
    for (int i = t; i < 1536; i += 512) {
        int m = i >> 9;
        int rem = i & 511;
        int f = rem >> 6;
        int L = rem & 63;
        int kb = (f >> 2) * 32 + (L >> 4) * 8;
        int o = (f & 3) * 16 + (L & 15);
        const float* Wsrc = (m == 0) ? W1 : (m == 1) ? Wl1 : Wr1;
        unsigned short* dst = &sW[m][f * 512 + L * 8];
        #pragma unroll
        for (int j = 0; j < 8; ++j) dst[j] = f2bf(Wsrc[(kb + j) * 64 + o]);
    }
    __syncthreads();

    int lane = t & 63;
    int wave = t >> 6;
    int quad = lane >> 4;
    int n16 = lane & 15;
    int base = blockIdx.x * 128 + wave * 16;
    if (base >= N) return;

    int nm = base + n16;
    if (nm >= N) nm = N - 1;
    const unsigned short* ar = agg + (size_t)nm * 128;

    {
        short8 a0 = *(const short8*)(ar + quad * 8);
        short8 a1 = *(const short8*)(ar + 32 + quad * 8);
        floatx4 g0 = {0.f, 0.f, 0.f, 0.f}, g1 = g0, g2 = g0, g3 = g0;
        g0 = __builtin_amdgcn_mfma_f32_16x16x32_bf16(a0, *(const short8*)&sW[0][0 * 512 + lane * 8], g0, 0, 0, 0);
        g0 = __builtin_amdgcn_mfma_f32_16x16x32_bf16(a1, *(const short8*)&sW[0][4 * 512 + lane * 8], g0, 0, 0, 0);
        g1 = __builtin_amdgcn_mfma_f32_16x16x32_bf16(a0, *(const short8*)&sW[0][1 * 512 + lane * 8], g1, 0, 0, 0);
        g1 = __builtin_amdgcn_mfma_f32_16x16x32_bf16(a1, *(const short8*)&sW[0][5 * 512 + lane * 8], g1, 0, 0, 0);
        g2 = __builtin_amdgcn_mfma_f32_16x16x32_bf16(a0, *(const short8*)&sW[0][2 * 512 + lane * 8], g2, 0, 0, 0);
        g2 = __builtin_amdgcn_mfma_f32_16x16x32_bf16(a1, *(const short8*)&sW[0][6 * 512 + lane * 8], g2, 0, 0, 0);
        g3 = __builtin_amdgcn_mfma_f32_16x16x32_bf16(a0, *(const short8*)&sW[0][3 * 512 + lane * 8], g3, 0, 0, 0);
        g3 = __builtin_amdgcn_mfma_f32_16x16x32_bf16(a1, *(const short8*)&sW[0][7 * 512 + lane * 8], g3, 0, 0, 0);
        floatx4 gt[4] = {g0, g1, g2, g3};
        #pragma unroll
        for (int nt = 0; nt < 4; ++nt) {
            float bg = b1[nt * 16 + n16];
            #pragma unroll
            for (int r = 0; r < 4; ++r) {
                int node = base + quad * 4 + r;
                if (node < N)
                    buf1[(size_t)node * 128 + nt * 16 + n16] = f2bf(fmaxf(gt[nt][r] + bg, 0.f));
            }
        }
    }

    {
        short8 a0 = *(const short8*)(ar + 64 + quad * 8);
        short8 a1 = *(const short8*)(ar + 96 + quad * 8);
        short8 ax0 = *(const short8*)&xb[(size_t)nm * 64 + quad * 8];
        short8 ax1 = *(const short8*)&xb[(size_t)nm * 64 + 32 + quad * 8];

        floatx4 s0 = {0.f, 0.f, 0.f, 0.f}, s1 = s0, s2 = s0, s3 = s0;
        s0 = __builtin_amdgcn_mfma_f32_16x16x32_bf16(a0, *(const short8*)&sW[1][0 * 512 + lane * 8], s0, 0, 0, 0);
        s0 = __builtin_amdgcn_mfma_f32_16x16x32_bf16(a1, *(const short8*)&sW[1][4 * 512 + lane * 8], s0, 0, 0, 0);
        s0 = __builtin_amdgcn_mfma_f32_16x16x32_bf16(ax0, *(const short8*)&sW[2][0 * 512 + lane * 8], s0, 0, 0, 0);
        s0 = __builtin_amdgcn_mfma_f32_16x16x32_bf16(ax1, *(const short8*)&sW[2][4 * 512 + lane * 8], s0, 0, 0, 0);
        s1 = __builtin_amdgcn_mfma_f32_16x16x32_bf16(a0, *(const short8*)&sW[1][1 * 512 + lane * 8], s1, 0, 0, 0);
        s1 = __builtin_amdgcn_mfma_f32_16x16x32_bf16(a1, *(const short8*)&sW[1][5 * 512 + lane * 8], s1, 0, 0, 0);
        s1 = __builtin_amdgcn_mfma_f32_16x16x32_bf16(ax0, *(const short8*)&sW[2][1 * 512 + lane * 8], s1, 0, 0, 0);
        s1 = __builtin_amdgcn_mfma_f32_16x16x32_bf16(ax1, *(const short8*)&sW[2][5 * 512 + lane * 8], s1, 0, 0, 0);
        s2 = __builtin_amdgcn_mfma_f32_16x16x32_bf16(a0, *(const short8*)&sW[1][2 * 512 + lane * 8], s2, 0, 0, 0);
        s2 = __builtin_amdgcn_mfma_f32_16x16x32_bf16(a1, *(const short8*)&sW[1][6 * 512 + lane * 8], s2, 0, 0, 0);
        s2 = __builtin_amdgcn_mfma_f32_16x16x32_bf16(ax0, *(const short8*)&sW[2][2 * 512 + lane * 8], s2, 0, 0, 0);
        s2 = __builtin_amdgcn_mfma_f32_16x16x32_bf16(ax1, *(const short8*)&sW[2][6 * 512 + lane * 8], s2, 0, 0, 0);
        s3 = __builtin_amdgcn_mfma_f32_16x16x32_bf16(a0, *(const short8*)&sW[1][3 * 512 + lane * 8], s3, 0, 0, 0);
        s3 = __builtin_amdgcn_mfma_f32_16x16x32_bf16(a1, *(const short8*)&sW[1][7 * 512 + lane * 8], s3, 0, 0, 0);
        s3 = __builtin_amdgcn_mfma_f32_16x16x32_bf16(ax0, *(const short8*)&sW[2][3 * 512 + lane * 8], s3, 0, 0, 0);
        s3 = __builtin_amdgcn_mfma_f32_16x16x32_bf16(ax1, *(const short8*)&sW[2][7 * 512 + lane * 8], s3, 0, 0, 0);
        floatx4 stl[4] = {s0, s1, s2, s3};
        #pragma unroll
        for (int nt = 0; nt < 4; ++nt) {
            float bs = bl1[nt * 16 + n16];
            #pragma unroll
            for (int r = 0; r < 4; ++r) {
                int node = base + quad * 4 + r;
                if (node < N)
                    buf1[(size_t)node * 128 + 64 + nt * 16 + n16] = f2bf(fmaxf(stl[nt][r] + bs, 0.f));
            }
        }
    }
}

// Layer-2 GEMMs + LN + concat-proj via MFMA (proven in R8).
__launch_bounds__(512, 1)
__global__ void k_gemm2(const unsigned short* __restrict__ agg,
                        const unsigned short* __restrict__ buf1,
                        const float* __restrict__ W2, const float* __restrict__ b2,
                        const float* __restrict__ Wl2, const float* __restrict__ bl2,
                        const float* __restrict__ Wr2,
                        const float* __restrict__ lngG, const float* __restrict__ lnbG,
                        const float* __restrict__ lngS, const float* __restrict__ lnbS,
                        const float* __restrict__ Pw, const float* __restrict__ Pb,
                        float* __restrict__ out, int N) {
    alignas(16) __shared__ unsigned short sW[3][4096];
    alignas(16) __shared__ unsigned short sP[8192];
    alignas(16) __shared__ unsigned short sT[8][16 * 132];
    int t = threadIdx.x;
    for (int i = t; i < 1536; i += 512) {
        int m = i >> 9;
        int rem = i & 511;
        int f = rem >> 6;
        int L = rem & 63;
        int kb = (f >> 2) * 32 + (L >> 4) * 8;
        int o = (f & 3) * 16 + (L & 15);
        const float* Wsrc = (m == 0) ? W2 : (m == 1) ? Wl2 : Wr2;
        unsigned short* dst = &sW[m][f * 512 + L * 8];
        #pragma unroll
        for (int j = 0; j < 8; ++j) dst[j] = f2bf(Wsrc[(kb + j) * 64 + o]);
    }
    for (int i = t; i < 1024; i += 512) {
        int f = i >> 6;
        int L = i & 63;
        int kb = (f >> 2) * 32 + (L >> 4) * 8;
        int o = (f & 3) * 16 + (L & 15);
        unsigned short* dst = &sP[f * 512 + L * 8];
        #pragma unroll
        for (int j = 0; j < 8; ++j) dst[j] = f2bf(Pw[(kb + j) * 64 + o]);
    }
    __syncthreads();

    int lane = t & 63;
    int wave = t >> 6;
    int quad = lane >> 4;
    int n16 = lane & 15;
    int base = blockIdx.x * 128 + wave * 16;
    if (base >= N) return;
    int nm = base + n16;
    if (nm >= N) nm = N - 1;
    const unsigned short* ar = agg + (size_t)nm * 128;
    const unsigned short* br = buf1 + (size_t)nm * 128;
    unsigned short* tw = &sT[wave][0];

    {
        short8 a0 = *(const short8*)(ar + quad * 8);
        short8 a1 = *(const short8*)(ar + 32 + quad * 8);
        floatx4 c0 = {0.f, 0.f, 0.f, 0.f}, c1 = c0, c2 = c0, c3 = c0;
        c0 = __builtin_amdgcn_mfma_f32_16x16x32_bf16(a0, *(const short8*)&sW[0][0 * 512 + lane * 8], c0, 0, 0, 0);
        c0 = __builtin_amdgcn_mfma_f32_16x16x32_bf16(a1, *(const short8*)&sW[0][4 * 512 + lane * 8], c0, 0, 0, 0);
        c1 = __builtin_amdgcn_mfma_f32_16x16x32_bf16(a0, *(const short8*)&sW[0][1 * 512 + lane * 8], c1, 0, 0, 0);
        c1 = __builtin_amdgcn_mfma_f32_16x16x32_bf16(a1, *(const short8*)&sW[0][5 * 512 + lane * 8], c1, 0, 0, 0);
        c2 = __builtin_amdgcn_mfma_f32_16x16x32_bf16(a0, *(const short8*)&sW[0][2 * 512 + lane * 8], c2, 0, 0, 0);
        c2 = __builtin_amdgcn_mfma_f32_16x16x32_bf16(a1, *(const short8*)&sW[0][6 * 512 + lane * 8], c2, 0, 0, 0);
        c3 = __builtin_amdgcn_mfma_f32_16x16x32_bf16(a0, *(const short8*)&sW[0][3 * 512 + lane * 8], c3, 0, 0, 0);
        c3 = __builtin_amdgcn_mfma_f32_16x16x32_bf16(a1, *(const short8*)&sW[0][7 * 512 + lane * 8], c3, 0, 0, 0);

        float bv0 = b2[n16], bv1 = b2[16 + n16], bv2 = b2[32 + n16], bv3 = b2[48 + n16];
        float gv0 = lngG[n16], gv1 = lngG[16 + n16], gv2 = lngG[32 + n16], gv3 = lngG[48 + n16];
        float ev0 = lnbG[n16], ev1 = lnbG[16 + n16], ev2 = lnbG[32 + n16], ev3 = lnbG[48 + n16];
        #pragma unroll
        for (int r = 0; r < 4; ++r) {
            float z0 = c0[r] + bv0, z1 = c1[r] + bv1, z2 = c2[r] + bv2, z3 = c3[r] + bv3;
            float s = red16(z0 + z1 + z2 + z3);
            float q = red16(z0 * z0 + z1 * z1 + z2 * z2 + z3 * z3);
            float mu = s * (1.0f / 64.0f);
            float var = fmaxf(q * (1.0f / 64.0f) - mu * mu, 0.0f);
            float rs = rsqrtf(var + 1e-5f);
            unsigned short* row = tw + (quad * 4 + r) * 132;
            row[n16]      = f2bf((z0 - mu) * rs * gv0 + ev0);
            row[16 + n16] = f2bf((z1 - mu) * rs * gv1 + ev1);
            row[32 + n16] = f2bf((z2 - mu) * rs * gv2 + ev2);
            row[48 + n16] = f2bf((z3 - mu) * rs * gv3 + ev3);
        }
    }

    {
        short8 a0 = *(const short8*)(ar + 64 + quad * 8);
        short8 a1 = *(const short8*)(ar + 96 + quad * 8);
        short8 v0 = *(const short8*)(br + 64 + quad * 8);
        short8 v1 = *(const short8*)(br + 96 + quad * 8);
        floatx4 c0 = {0.f, 0.f, 0.f, 0.f}, c1 = c0, c2 = c0, c3 = c0;
        c0 = __builtin_amdgcn_mfma_f32_16x16x32_bf16(a0, *(const short8*)&sW[1][0 * 512 + lane * 8], c0, 0, 0, 0);
        c0 = __builtin_amdgcn_mfma_f32_16x16x32_bf16(a1, *(const short8*)&sW[1][4 * 512 + lane * 8], c0, 0, 0, 0);
        c0 = __builtin_amdgcn_mfma_f32_16x16x32_bf16(v0, *(const short8*)&sW[2][0 * 512 + lane * 8], c0, 0, 0, 0);
        c0 = __builtin_amdgcn_mfma_f32_16x16x32_bf16(v1, *(const short8*)&sW[2][4 * 512 + lane * 8], c0, 0, 0, 0);
        c1 = __builtin_amdgcn_mfma_f32_16x16x32_bf16(a0, *(const short8*)&sW[1][1 * 512 + lane * 8], c1, 0, 0, 0);
        c1 = __builtin_amdgcn_mfma_f32_16x16x32_bf16(a1, *(const short8*)&sW[1][5 * 512 + lane * 8], c1, 0, 0, 0);
        c1 = __builtin_amdgcn_mfma_f32_16x16x32_bf16(v0, *(const short8*)&sW[2][1 * 512 + lane * 8], c1, 0, 0, 0);
        c1 = __builtin_amdgcn_mfma_f32_16x16x32_bf16(v1, *(const short8*)&sW[2][5 * 512 + lane * 8], c1, 0, 0, 0);
        c2 = __builtin_amdgcn_mfma_f32_16x16x32_bf16(a0, *(const short8*)&sW[1][2 * 512 + lane * 8], c2, 0, 0, 0);
        c2 = __builtin_amdgcn_mfma_f32_16x16x32_bf16(a1, *(const short8*)&sW[1][6 * 512 + lane * 8], c2, 0, 0, 0);
        c2 = __builtin_amdgcn_mfma_f32_16x16x32_bf16(v0, *(const short8*)&sW[2][2 * 512 + lane * 8], c2, 0, 0, 0);
        c2 = __builtin_amdgcn_mfma_f32_16x16x32_bf16(v1, *(const short8*)&sW[2][6 * 512 + lane * 8], c2, 0, 0, 0);
        c3 = __builtin_amdgcn_mfma_f32_16x16x32_bf16(a0, *(const short8*)&sW[1][3 * 512 + lane * 8], c3, 0, 0, 0);
        c3 = __builtin_amdgcn_mfma_f32_16x16x32_bf16(a1, *(const short8*)&sW[1][7 * 512 + lane * 8], c3, 0, 0, 0);
        c3 = __builtin_amdgcn_mfma_f32_16x16x32_bf16(v0, *(const short8*)&sW[2][3 * 512 + lane * 8], c3, 0, 0, 0);
        c3 = __builtin_amdgcn_mfma_f32_16x16x32_bf16(v1, *(const short8*)&sW[2][7 * 512 + lane * 8], c3, 0, 0, 0);

        float bv0 = bl2[n16], bv1 = bl2[16 + n16], bv2 = bl2[32 + n16], bv3 = bl2[48 + n16];
        float gv0 = lngS[n16], gv1 = lngS[16 + n16], gv2 = lngS[32 + n16], gv3 = lngS[48 + n16];
        float ev0 = lnbS[n16], ev1 = lnbS[16 + n16], ev2 = lnbS[32 + n16], ev3 = lnbS[48 + n16];
        #pragma unroll
        for (int r = 0; r < 4; ++r) {
            float z0 = c0[r] + bv0, z1 = c1[r] + bv1, z2 = c2[r] + bv2, z3 = c3[r] + bv3;
            float s = red16(z0 + z1 + z2 + z3);
            float q = red16(z0 * z0 + z1 * z1 + z2 * z2 + z3 * z3);
            float mu = s * (1.0f / 64.0f);
            float var = fmaxf(q * (1.0f / 64.0f) - mu * mu, 0.0f);
            float rs = rsqrtf(var + 1e-5f);
            unsigned short* row = tw + (quad * 4 + r) * 132 + 64;
            row[n16]      = f2bf((z0 - mu) * rs * gv0 + ev0);
            row[16 + n16] = f2bf((z1 - mu) * rs * gv1 + ev1);
            row[32 + n16] = f2bf((z2 - mu) * rs * gv2 + ev2);
            row[48 + n16] = f2bf((z3 - mu) * rs * gv3 + ev3);
        }
    }

    floatx4 o0 = {0.f, 0.f, 0.f, 0.f}, o1 = o0, o2 = o0, o3 = o0;
    #pragma unroll
    for (int ks = 0; ks < 4; ++ks) {
        const unsigned short* ap = tw + n16 * 132 + ks * 32 + quad * 8;
        short4v lo = *(const short4v*)ap;
        short4v hi = *(const short4v*)(ap + 4);
        short8 af;
        af[0] = lo[0]; af[1] = lo[1]; af[2] = lo[2]; af[3] = lo[3];
        af[4] = hi[0]; af[5] = hi[1]; af[6] = hi[2]; af[7] = hi[3];
        o0 = __builtin_amdgcn_mfma_f32_16x16x32_bf16(af, *(const short8*)&sP[(ks * 4 + 0) * 512 + lane * 8], o0, 0, 0, 0);
        o1 = __builtin_amdgcn_mfma_f32_16x16x32_bf16(af, *(const short8*)&sP[(ks * 4 + 1) * 512 + lane * 8], o1, 0, 0, 0);
        o2 = __builtin_amdgcn_mfma_f32_16x16x32_bf16(af, *(const short8*)&sP[(ks * 4 + 2) * 512 + lane * 8], o2, 0, 0, 0);
        o3 = __builtin_amdgcn_mfma_f32_16x16x32_bf16(af, *(const short8*)&sP[(ks * 4 + 3) * 512 + lane * 8], o3, 0, 0, 0);
    }
    float p0 = Pb[n16], p1 = Pb[16 + n16], p2 = Pb[32 + n16], p3 = Pb[48 + n16];
    floatx4 ot[4] = {o0, o1, o2, o3};
    float pv[4] = {p0, p1, p2, p3};
    #pragma unroll
    for (int nt = 0; nt < 4; ++nt) {
        #pragma unroll
        for (int r = 0; r < 4; ++r) {
            int node = base + quad * 4 + r;
            if (node < N) out[(size_t)node * 64 + nt * 16 + n16] = ot[nt][r] + pv[nt];
        }
    }
}

extern "C" void kernel_launch(void* const* d_in, const int* in_sizes, int n_in,
                              void* d_out, int out_size, void* d_ws, size_t ws_size,
                              hipStream_t stream) {
    const float* x        = (const float*)d_in[0];
    const int*   ei       = (const int*)d_in[1];
    const float* gcn_w1   = (const float*)d_in[2];
    const float* gcn_b1   = (const float*)d_in[3];
    const float* gcn_w2   = (const float*)d_in[4];
    const float* gcn_b2   = (const float*)d_in[5];
    const float* sage_wl1 = (const float*)d_in[6];
    const float* sage_bl1 = (const float*)d_in[7];
    const float* sage_wr1 = (const float*)d_in[8];
    const float* sage_wl2 = (const float*)d_in[9];
    const float* sage_bl2 = (const float*)d_in[10];
    const float* sage_wr2 = (const float*)d_in[11];
    const float* gcn_ln_g = (const float*)d_in[12];
    const float* gcn_ln_b = (const float*)d_in[13];
    const float* sage_ln_g = (const float*)d_in[14];
    const float* sage_ln_b = (const float*)d_in[15];
    const float* proj_w   = (const float*)d_in[16];
    const float* proj_b   = (const float*)d_in[17];
    float* out = (float*)d_out;

    const int N = in_sizes[0] / 64;
    const int E = in_sizes[1] / 2;
    const int G = (N + 15) / 16;
    const int Bg = (G + SCAN_CHUNK - 1) / SCAN_CHUNK;

    char* w = (char*)d_ws;
    size_t off = 0;
    auto alloc = [&](size_t bytes) -> void* {
        void* p = w + off;
        off = (off + bytes + 255) & ~(size_t)255;
        return p;
    };
    int*            cnt       = (int*)alloc((size_t)N * 4);
    int*            offs16    = (int*)alloc((size_t)(G + 1) * 4);
    float*          dinv      = (float*)alloc((size_t)N * 4);
    int*            blockSums = (int*)alloc((size_t)(Bg + 1) * 4);
    int*            cnt16     = (int*)alloc((size_t)G * 4);
    int*            csr       = (int*)alloc((size_t)(E + 16 * G + 64) * 4);
    unsigned int*   pk        = (unsigned int*)alloc((size_t)(E + 16 * G + 64) * 4);
    unsigned int*   counts    = (unsigned int*)alloc((size_t)NB * G * 4);
    unsigned short* agg       = (unsigned short*)alloc((size_t)N * 128 * 2);
    unsigned short* buf1      = (unsigned short*)alloc((size_t)N * 128 * 2);
    unsigned short* xb        = (unsigned short*)alloc((size_t)N * 64 * 2);
    (void)n_in; (void)out_size; (void)ws_size;

    k_hist<<<NB, 256, 0, stream>>>(ei, E, G, counts, x, xb, N * 64);
    k_colsum<<<(G + 255) / 256, 256, 0, stream>>>(counts, G, cnt16);
    k_gr<<<Bg, 256, 0, stream>>>(cnt16, G, blockSums);
    k_scan_spine<<<1, 64, 0, stream>>>(blockSums, Bg);
    k_gw<<<Bg, 256, 0, stream>>>(cnt16, G, blockSums, offs16);
    k_bases<<<(G + 255) / 256, 256, 0, stream>>>(counts, G, offs16);
    k_scatter<<<NB, 256, 0, stream>>>(ei, E, G, counts, csr, pk);
    k_degself<<<(G + 3) / 4, 256, 0, stream>>>(offs16, G, N, cnt, dinv, csr, pk);
    k_weights<<<(G + 3) / 4, 256, 0, stream>>>(csr, offs16, G, N, dinv, pk);

    k_gatherM<64><<<(N + 63) / 64, 256, 0, stream>>>(xb, csr, pk, offs16, cnt, agg, N);
    k_gemm1<<<(N + 127) / 128, 512, 0, stream>>>(agg, xb, gcn_w1, gcn_b1,
                                                 sage_wl1, sage_bl1, sage_wr1, buf1, N);
    k_gatherM<128><<<(N + 63) / 64, 256, 0, stream>>>(buf1, csr, pk, offs16, cnt, agg, N);
    k_gemm2<<<(N + 127) / 128, 512, 0, stream>>>(agg, buf1, gcn_w2, gcn_b2,
                                                 sage_wl2, sage_bl2, sage_wr2,
                                                 gcn_ln_g, gcn_ln_b, sage_ln_g, sage_ln_b,
                                                 proj_w, proj_b, out, N);
}

// Round 10
// 328.433 us; speedup vs baseline: 1.1089x; 1.0144x over previous
//
#include <hip/hip_runtime.h>

// N=100000 nodes, E=1250000 edges, all dims 64.
// R19: R18 (333us, atomic-free preprocessing) top dispatch is gatherM<128>
// again (53us, latency-bound serial chunk chain, Mfma 4%/VALU 20%/occ 30%).
// Pipelining failed twice (R11/R13); instead HALVE the serial chain:
// 2 waves per group (wave A: even chunks, B: odd chunks), independent f32
// accumulators, pairwise LDS reduce (two 4KB phases in B's staging buffer),
// A does the epilogue. Body/VGPR/LDS identical; grid doubles; 4 barriers.
// Preprocessing + GEMMs byte-identical to R18.

#define SCAN_CHUNK 2048
#define NB 256        // histogram/scatter blocks
#define GMAX 8192     // max groups (N <= 131072)

typedef __attribute__((ext_vector_type(8))) short short8;   // 8 bf16 = 4 VGPRs
typedef __attribute__((ext_vector_type(4))) short short4v;  // 4 bf16 = 2 VGPRs
typedef __attribute__((ext_vector_type(4))) float floatx4;  // MFMA C/D

__device__ __forceinline__ unsigned short f2bf(float f) {
    unsigned int u = __float_as_uint(f);
    unsigned int r = u + 0x7FFFu + ((u >> 16) & 1u);  // round-to-nearest-even
    return (unsigned short)(r >> 16);
}
__device__ __forceinline__ float bf2f(unsigned short h) {
    return __uint_as_float(((unsigned int)h) << 16);
}

__device__ __forceinline__ unsigned lds_addr(const void* p) {
    return (unsigned)(unsigned long long)(__attribute__((address_space(3))) const char*)p;
}

__device__ __forceinline__ short8 cat44(short4v lo, short4v hi) {
    short8 r;
    r[0] = lo[0]; r[1] = lo[1]; r[2] = lo[2]; r[3] = lo[3];
    r[4] = hi[0]; r[5] = hi[1]; r[6] = hi[2]; r[7] = hi[3];
    return r;
}

// Read 4 B-frags (col-tiles CTB..CTB+3) for this lane's k-group via HW transpose.
// LDS holds 32xROWSH bf16 tile subtiled [k/4][f/16][4][16]; subtile s at byte s*128.
// a0 = wb_base + (q*2*NF)*128 + (lane&15)*8.
template<int NF, int CTB>
__device__ __forceinline__ void tr_read4(unsigned a0, short8 bf[4]) {
    short4v l0, h0, l1, h1, l2, h2, l3, h3;
    asm volatile(
        "ds_read_b64_tr_b16 %0, %8 offset:%9\n\t"
        "ds_read_b64_tr_b16 %1, %8 offset:%10\n\t"
        "ds_read_b64_tr_b16 %2, %8 offset:%11\n\t"
        "ds_read_b64_tr_b16 %3, %8 offset:%12\n\t"
        "ds_read_b64_tr_b16 %4, %8 offset:%13\n\t"
        "ds_read_b64_tr_b16 %5, %8 offset:%14\n\t"
        "ds_read_b64_tr_b16 %6, %8 offset:%15\n\t"
        "ds_read_b64_tr_b16 %7, %8 offset:%16\n\t"
        "s_waitcnt lgkmcnt(0)"
        : "=&v"(l0), "=&v"(h0), "=&v"(l1), "=&v"(h1),
          "=&v"(l2), "=&v"(h2), "=&v"(l3), "=&v"(h3)
        : "v"(a0),
          "i"((0 * NF + CTB + 0) * 128), "i"((1 * NF + CTB + 0) * 128),
          "i"((0 * NF + CTB + 1) * 128), "i"((1 * NF + CTB + 1) * 128),
          "i"((0 * NF + CTB + 2) * 128), "i"((1 * NF + CTB + 2) * 128),
          "i"((0 * NF + CTB + 3) * 128), "i"((1 * NF + CTB + 3) * 128)
        : "memory");
    bf[0] = cat44(l0, h0);
    bf[1] = cat44(l1, h1);
    bf[2] = cat44(l2, h2);
    bf[3] = cat44(l3, h3);
}

// per-block LDS group histogram (no global atomics); fused x->bf16
__global__ void k_hist(const int* __restrict__ ei, int E, int G,
                       unsigned* __restrict__ counts,
                       const float* __restrict__ x, unsigned short* __restrict__ xb,
                       int xtotal) {
    __shared__ unsigned hist[GMAX];
    int t = threadIdx.x, b = blockIdx.x;
    for (int i = t; i < G; i += 256) hist[i] = 0;
    __syncthreads();
    int ec = (E + NB - 1) / NB;
    int lo = b * ec, hi = min(lo + ec, E);
    for (int idx = lo + t; idx < hi; idx += 256)
        atomicAdd(&hist[ei[E + idx] >> 4], 1u);
    __syncthreads();
    for (int i = t; i < G; i += 256) counts[(size_t)b * G + i] = hist[i];
    int nv = xtotal >> 3;
    for (int v = b * 256 + t; v < nv; v += NB * 256) {
        int e = v * 8;
        float4 a = *(const float4*)&x[e];
        float4 c = *(const float4*)&x[e + 4];
        short8 o;
        o[0] = (short)f2bf(a.x); o[1] = (short)f2bf(a.y);
        o[2] = (short)f2bf(a.z); o[3] = (short)f2bf(a.w);
        o[4] = (short)f2bf(c.x); o[5] = (short)f2bf(c.y);
        o[6] = (short)f2bf(c.z); o[7] = (short)f2bf(c.w);
        *(short8*)&xb[e] = o;
    }
}

// cnt16[g] = sum over blocks of counts[b][g] (coalesced across g)
__global__ void k_colsum(const unsigned* __restrict__ counts, int G,
                         int* __restrict__ cnt16) {
    int g = blockIdx.x * 256 + threadIdx.x;
    if (g < G) {
        int tot = 0;
        for (int b = 0; b < NB; ++b) tot += (int)counts[(size_t)b * G + g];
        cnt16[g] = tot;
    }
}

// scan over (cnt16[g] + 16): 16 self slots per group
__global__ void k_gr(const int* __restrict__ cnt16, int G, int* __restrict__ blockSums) {
    __shared__ int lds[256];
    int base = blockIdx.x * SCAN_CHUNK;
    int t = threadIdx.x;
    int s = 0;
    for (int j = 0; j < 8; ++j) {
        int idx = base + t * 8 + j;
        if (idx < G) s += cnt16[idx] + 16;
    }
    lds[t] = s;
    __syncthreads();
    for (int d = 128; d > 0; d >>= 1) {
        if (t < d) lds[t] += lds[t + d];
        __syncthreads();
    }
    if (t == 0) blockSums[blockIdx.x] = lds[0];
}

__global__ void k_scan_spine(int* __restrict__ blockSums, int B) {
    if (threadIdx.x == 0 && blockIdx.x == 0) {
        int run = 0;
        for (int b = 0; b < B; ++b) { int v = blockSums[b]; blockSums[b] = run; run += v; }
    }
}

__global__ void k_gw(const int* __restrict__ cnt16, int G,
                     const int* __restrict__ blockSums, int* __restrict__ offs16) {
    __shared__ int lds[256];
    int base = blockIdx.x * SCAN_CHUNK;
    int t = threadIdx.x;
    int v[8];
    int s = 0;
    for (int j = 0; j < 8; ++j) {
        int idx = base + t * 8 + j;
        v[j] = (idx < G) ? cnt16[idx] : 0;
        s += (idx < G) ? v[j] + 16 : 0;
    }
    lds[t] = s;
    __syncthreads();
    for (int d = 1; d < 256; d <<= 1) {
        int x = (t >= d) ? lds[t - d] : 0;
        __syncthreads();
        lds[t] += x;
        __syncthreads();
    }
    int excl = (t == 0) ? 0 : lds[t - 1];
    int run = blockSums[blockIdx.x] + excl;
    for (int j = 0; j < 8; ++j) {
        int idx = base + t * 8 + j;
        if (idx < G) {
            offs16[idx] = run;
            run += v[j] + 16;
            if (idx == G - 1) offs16[G] = run;
        }
    }
}

// counts[b][g] -> absolute base (in place): serial per-group thread.
// For fixed b, adjacent threads touch adjacent g -> fully coalesced.
__global__ void k_bases(unsigned* __restrict__ counts, int G,
                        const int* __restrict__ offs16) {
    int g = blockIdx.x * 256 + threadIdx.x;
    if (g >= G) return;
    unsigned run = (unsigned)offs16[g];
    for (int b = 0; b < NB; ++b) {
        unsigned v = counts[(size_t)b * G + g];
        counts[(size_t)b * G + g] = run;
        run += v;
    }
}

// scatter edges into group-bucketed CSR via LDS cursors (no global atomics)
__global__ void k_scatter(const int* __restrict__ ei, int E, int G,
                          const unsigned* __restrict__ counts,
                          int* __restrict__ csr, unsigned* __restrict__ pk) {
    __shared__ unsigned cur[GMAX];
    int t = threadIdx.x, b = blockIdx.x;
    for (int i = t; i < G; i += 256) cur[i] = counts[(size_t)b * G + i];
    __syncthreads();
    int ec = (E + NB - 1) / NB;
    int lo = b * ec, hi = min(lo + ec, E);
    for (int idx = lo + t; idx < hi; idx += 256) {
        int s = ei[idx];
        int d = ei[E + idx];
        unsigned pos = atomicAdd(&cur[d >> 4], 1u);  // LDS atomic
        csr[pos] = s;
        pk[pos] = (unsigned)(d & 15) << 16;
    }
}

// per-node degree via per-wave LDS counters (proven LDS-atomic mechanism);
// writes cnt/dinv and the 16 self slots (weight di^2, bit20 = SAGE-exclude).
__global__ void k_degself(const int* __restrict__ offs16, int G, int N,
                          int* __restrict__ cnt, float* __restrict__ dinv,
                          int* __restrict__ csr, unsigned* __restrict__ pk) {
    __shared__ int wcnt[4][16];
    int lane = threadIdx.x & 63;
    int wv = threadIdx.x >> 6;
    int g = blockIdx.x * 4 + wv;
    bool act = (g < G);
    if (lane < 16) wcnt[wv][lane] = 0;
    __syncthreads();
    if (act) {
        int lo = offs16[g];
        int rh = offs16[g + 1] - 16;
        for (int idx = lo + lane; idx < rh; idx += 64) {
            int d15 = (int)((pk[idx] >> 16) & 15u);
            atomicAdd(&wcnt[wv][d15], 1);
        }
    }
    __syncthreads();
    if (act && lane < 16) {
        int rh = offs16[g + 1] - 16;
        int deg = wcnt[wv][lane];
        int node = g * 16 + lane;
        int slot = rh + lane;
        if (node < N) {
            cnt[node] = deg;
            float di = rsqrtf((float)deg + 1.0f);
            dinv[node] = di;
            csr[slot] = node;
            pk[slot] = ((unsigned)lane << 16) | (1u << 20) | f2bf(di * di);
        } else {
            csr[slot] = 0;
            pk[slot] = ((unsigned)lane << 16) | (1u << 20);  // w=0, excluded
        }
    }
}

// fill pk weights: bf16(dinv[src] * dinv[dst]); dst = 16g + d15 (direct load)
__global__ void k_weights(const int* __restrict__ csr, const int* __restrict__ offs16,
                          int G, int N, const float* __restrict__ dinv,
                          unsigned* __restrict__ pk) {
    int lane = threadIdx.x & 63;
    int g = blockIdx.x * 4 + (threadIdx.x >> 6);
    if (g >= G) return;
    int lo = offs16[g];
    int rh = offs16[g + 1] - 16;
    for (int idx = lo + lane; idx < rh; idx += 64) {
        unsigned u = pk[idx];
        int s = csr[idx];
        int dst = g * 16 + (int)((u >> 16) & 15u);
        pk[idx] = u | f2bf(dinv[s] * dinv[dst]);
    }
}

// ===================== MFMA SpMM gather (2 waves per group) ===================
// Wave pair (half=0/1) splits a group's chunks (even/odd); independent f32
// accumulators; pairwise LDS reduce (two 4KB phases in half=1's staging
// buffer); half=0 runs the epilogue. Serial body identical to R18.
template<int ROWSH>
__launch_bounds__(256)
__global__ void k_gatherM(const unsigned short* __restrict__ feat,
                          const int* __restrict__ csr,
                          const unsigned int* __restrict__ pk,
                          const int* __restrict__ offs16, const int* __restrict__ cnt,
                          unsigned short* __restrict__ agg, int N) {
    constexpr int NF = ROWSH / 16;      // f-subtiles per edge row (4 or 8)
    constexpr int LPR = ROWSH / 8;      // lanes per staged row
    constexpr int EPP = 64 / LPR;       // edges per staging pass
    constexpr int PASSES = 32 / EPP;    // passes per 32-edge chunk (4 or 8)

    __shared__ unsigned short sbuf[4][32 * ROWSH];

    const int lane = threadIdx.x & 63;
    const int wv = threadIdx.x >> 6;
    const int pairid = wv >> 1;
    const int half = wv & 1;
    const int base = blockIdx.x * 32 + pairid * 16;
    const bool act = (base < N);

    const int q = lane >> 4;
    const int d16 = lane & 15;

    // conflict-free staging map: lane L holds the 16B that belongs at byte
    // p*1024 + 16L of the subtiled LDS image (bijection per 1024B pass block).
    const int parity = lane & 1;
    const int ei_low = (lane >> 1) & 3;
    const int sf_sub = (lane >> 3) & (NF - 1);
    const int ei_high = (NF == 8) ? 0 : (lane >> 5);
    const int eid = ei_high * 4 + ei_low;
    const int sf = sf_sub * 16 + parity * 8;

    int elo = 0, ehi = 0;
    if (act) {
        const int grp = base >> 4;
        elo = offs16[grp];
        ehi = offs16[grp + 1];
    }
    const int emax = ehi - 1;
    const int nch = act ? ((ehi - elo + 31) >> 5) : 0;

    // ---- resident meta: 4 windows of 64 edges (covers 8 chunks = 256 edges) ----
    int cM0 = 0, cM1 = 0, cM2 = 0, cM3 = 0;
    unsigned pM0 = 0x00100000u, pM1 = 0x00100000u, pM2 = 0x00100000u, pM3 = 0x00100000u;
    if (act) {
        int i0 = elo + lane;
        int i1 = i0 + 64, i2 = i0 + 128, i3 = i0 + 192;
        cM0 = csr[i0 <= emax ? i0 : emax];
        cM1 = csr[i1 <= emax ? i1 : emax];
        cM2 = csr[i2 <= emax ? i2 : emax];
        cM3 = csr[i3 <= emax ? i3 : emax];
        unsigned t0 = pk[i0 <= emax ? i0 : emax];
        unsigned t1 = pk[i1 <= emax ? i1 : emax];
        unsigned t2 = pk[i2 <= emax ? i2 : emax];
        unsigned t3 = pk[i3 <= emax ? i3 : emax];
        pM0 = (i0 < ehi) ? t0 : 0x00100000u;
        pM1 = (i1 < ehi) ? t1 : 0x00100000u;
        pM2 = (i2 < ehi) ? t2 : 0x00100000u;
        pM3 = (i3 < ehi) ? t3 : 0x00100000u;
    }

    floatx4 accg[4], accs[4];
#pragma unroll
    for (int i = 0; i < 4; ++i) {
        accg[i] = floatx4{0.f, 0.f, 0.f, 0.f};
        accs[i] = floatx4{0.f, 0.f, 0.f, 0.f};
    }

    unsigned short* wb = &sbuf[wv][0];
    const unsigned a0 = lds_addr(wb) + (unsigned)(q * 2 * NF) * 128u + (unsigned)d16 * 8u;

    for (int c = half; c < nch; c += 2) {
        // ---- meta for chunk c (resident regs; rare dynamic path >256 edges) ----
        int cv; unsigned pv; int wofs;
        int rc = c >> 1;
        if (rc < 4) {
            wofs = (c & 1) << 5;
            cv = (rc == 0) ? cM0 : (rc == 1) ? cM1 : (rc == 2) ? cM2 : cM3;
            pv = (rc == 0) ? pM0 : (rc == 1) ? pM1 : (rc == 2) ? pM2 : pM3;
        } else {
            int idx = elo + (c << 5) + lane;
            int idc = idx <= emax ? idx : emax;
            cv = csr[idc];
            unsigned t = pk[idc];
            pv = (idx < ehi) ? t : 0x00100000u;
            wofs = 0;
        }

        // ---- issue row loads (addresses from resident regs, no meta loads) ----
        short8 stg[PASSES];
#pragma unroll
        for (int p = 0; p < PASSES; ++p) {
            int src = __shfl(cv, wofs + p * EPP + eid, 64);
            stg[p] = *(const short8*)&feat[(size_t)src * ROWSH + sf];
        }

        // ---- A-frags (register-only; overlaps load latency) ----
        short8 aG, aS;
#pragma unroll
        for (int j = 0; j < 8; ++j) {
            unsigned u = (unsigned)__shfl((int)pv, wofs + q * 8 + j, 64);
            unsigned hi = u >> 16;
            bool match = (int)(hi & 15u) == d16;
            aG[j] = match ? (short)(u & 0xFFFFu) : (short)0;
            aS[j] = (match && !(hi & 16u)) ? (short)0x3F80 : (short)0;
        }

        // ---- conflict-free ds_write (compiler inserts vmcnt waits for stg) ----
#pragma unroll
        for (int p = 0; p < PASSES; ++p)
            *(short8*)&wb[p * 512 + lane * 8] = stg[p];
        asm volatile("s_waitcnt lgkmcnt(0)" ::: "memory");
        __builtin_amdgcn_sched_barrier(0);

        // ---- tr_read + MFMA ----
        short8 bG[4];
        tr_read4<NF, 0>(a0, bG);
#pragma unroll
        for (int ct = 0; ct < 4; ++ct)
            accg[ct] = __builtin_amdgcn_mfma_f32_16x16x32_bf16(aG, bG[ct], accg[ct], 0, 0, 0);
        if constexpr (NF == 8) {
            short8 bS[4];
            tr_read4<NF, 4>(a0, bS);
#pragma unroll
            for (int ct = 0; ct < 4; ++ct)
                accs[ct] = __builtin_amdgcn_mfma_f32_16x16x32_bf16(aS, bS[ct], accs[ct], 0, 0, 0);
        } else {
#pragma unroll
            for (int ct = 0; ct < 4; ++ct)
                accs[ct] = __builtin_amdgcn_mfma_f32_16x16x32_bf16(aS, bG[ct], accs[ct], 0, 0, 0);
        }
    }

    // ---- pairwise reduction: half==1 -> half==0 (two 4KB LDS phases) ----
    __syncthreads();
    if (act && half == 1) {
        float* dst = (float*)&sbuf[wv][0];
#pragma unroll
        for (int i = 0; i < 4; ++i)
#pragma unroll
            for (int r = 0; r < 4; ++r)
                dst[(i * 4 + r) * 64 + lane] = accg[i][r];
    }
    __syncthreads();
    if (act && half == 0) {
        const float* src = (const float*)&sbuf[wv + 1][0];
#pragma unroll
        for (int i = 0; i < 4; ++i)
#pragma unroll
            for (int r = 0; r < 4; ++r)
                accg[i][r] += src[(i * 4 + r) * 64 + lane];
    }
    __syncthreads();
    if (act && half == 1) {
        float* dst = (float*)&sbuf[wv][0];
#pragma unroll
        for (int i = 0; i < 4; ++i)
#pragma unroll
            for (int r = 0; r < 4; ++r)
                dst[(i * 4 + r) * 64 + lane] = accs[i][r];
    }
    __syncthreads();
    if (act && half == 0) {
        const float* src = (const float*)&sbuf[wv + 1][0];
#pragma unroll
        for (int i = 0; i < 4; ++i)
#pragma unroll
            for (int r = 0; r < 4; ++r)
                accs[i][r] += src[(i * 4 + r) * 64 + lane];

        // ---- epilogue: C/D layout row=(q*4+r), col=d16 ----
#pragma unroll
        for (int r = 0; r < 4; ++r) {
            int node = base + q * 4 + r;
            if (node < N) {
                float rn = 1.0f / fmaxf((float)cnt[node], 1.0f);
#pragma unroll
                for (int ct = 0; ct < 4; ++ct) {
                    agg[(size_t)node * 128 + ct * 16 + d16]      = f2bf(accg[ct][r]);
                    agg[(size_t)node * 128 + 64 + ct * 16 + d16] = f2bf(accs[ct][r] * rn);
                }
            }
        }
    }
}

__device__ __forceinline__ float red16(float v) {
    v += __shfl_xor(v, 1, 64);
    v += __shfl_xor(v, 2, 64);
    v += __shfl_xor(v, 4, 64);
    v += __shfl_xor(v, 8, 64);
    return v;
}

// Layer-1 GEMMs via MFMA.
__launch_bounds__(512, 1)
__global__ void k_gemm1(const unsigned short* __restrict__ agg,
                        const unsigned short* __restrict__ xb,
                        const float* __restrict__ W1, const float* __restrict__ b1,
                        const float* __restrict__ Wl1, const float* __restrict__ bl1,
                        const float* __restrict__ Wr1,
                        unsigned short* __restrict__ buf1, int N) {
    alignas(16) __shared__ unsigned short sW[3][4096];
    int t = threadIdx.x;
    for (int i = t; i < 1536; i += 512) {
        int m = i >> 9;
        int rem = i & 511;
        int f = rem >> 6;
        int L = rem & 63;
        int kb = (f >> 2) * 32 + (L >> 4) * 8;
        int o = (f & 3) * 16 + (L & 15);
        const float* Wsrc = (m == 0) ? W1 : (m == 1) ? Wl1 : Wr1;
        unsigned short* dst = &sW[m][f * 512 + L * 8];
        #pragma unroll
        for (int j = 0; j < 8; ++j) dst[j] = f2bf(Wsrc[(kb + j) * 64 + o]);
    }
    __syncthreads();

    int lane = t & 63;
    int wave = t >> 6;
    int quad = lane >> 4;
    int n16 = lane & 15;
    int base = blockIdx.x * 128 + wave * 16;
    if (base >= N) return;

    int nm = base + n16;
    if (nm >= N) nm = N - 1;
    const unsigned short* ar = agg + (size_t)nm * 128;

    {
        short8 a0 = *(const short8*)(ar + quad * 8);
        short8 a1 = *(const short8*)(ar + 32 + quad * 8);
        floatx4 g0 = {0.f, 0.f, 0.f, 0.f}, g1 = g0, g2 = g0, g3 = g0;
        g0 = __builtin_amdgcn_mfma_f32_16x16x32_bf16(a0, *(const short8*)&sW[0][0 * 512 + lane * 8], g0, 0, 0, 0);
        g0 = __builtin_amdgcn_mfma_f32_16x16x32_bf16(a1, *(const short8*)&sW[0][4 * 512 + lane * 8], g0, 0, 0, 0);
        g1 = __builtin_amdgcn_mfma_f32_16x16x32_bf16(a0, *(const short8*)&sW[0][1 * 512 + lane * 8], g1, 0, 0, 0);
        g1 = __builtin_amdgcn_mfma_f32_16x16x32_bf16(a1, *(const short8*)&sW[0][5 * 512 + lane * 8], g1, 0, 0, 0);
        g2 = __builtin_amdgcn_mfma_f32_16x16x32_bf16(a0, *(const short8*)&sW[0][2 * 512 + lane * 8], g2, 0, 0, 0);
        g2 = __builtin_amdgcn_mfma_f32_16x16x32_bf16(a1, *(const short8*)&sW[0][6 * 512 + lane * 8], g2, 0, 0, 0);
        g3 = __builtin_amdgcn_mfma_f32_16x16x32_bf16(a0, *(const short8*)&sW[0][3 * 512 + lane * 8], g3, 0, 0, 0);
        g3 = __builtin_amdgcn_mfma_f32_16x16x32_bf16(a1, *(const short8*)&sW[0][7 * 512 + lane * 8], g3, 0, 0, 0);
        floatx4 gt[4] = {g0, g1, g2, g3};
        #pragma unroll
        for (int nt = 0; nt < 4; ++nt) {
            float bg = b1[nt * 16 + n16];
            #pragma unroll
            for (int r = 0; r < 4; ++r) {
                int node = base + quad * 4 + r;
                if (node < N)
                    buf1[(size_t)node * 128 + nt * 16 + n16] = f2bf(fmaxf(gt[nt][r] + bg, 0.f));
            }
        }
    }

    {
        short8 a0 = *(const short8*)(ar + 64 + quad * 8);
        short8 a1 = *(const short8*)(ar + 96 + quad * 8);
        short8 ax0 = *(const short8*)&xb[(size_t)nm * 64 + quad * 8];
        short8 ax1 = *(const short8*)&xb[(size_t)nm * 64 + 32 + quad * 8];

        floatx4 s0 = {0.f, 0.f, 0.f, 0.f}, s1 = s0, s2 = s0, s3 = s0;
        s0 = __builtin_amdgcn_mfma_f32_16x16x32_bf16(a0, *(const short8*)&sW[1][0 * 512 + lane * 8], s0, 0, 0, 0);
        s0 = __builtin_amdgcn_mfma_f32_16x16x32_bf16(a1, *(const short8*)&sW[1][4 * 512 + lane * 8], s0, 0, 0, 0);
        s0 = __builtin_amdgcn_mfma_f32_16x16x32_bf16(ax0, *(const short8*)&sW[2][0 * 512 + lane * 8], s0, 0, 0, 0);
        s0 = __builtin_amdgcn_mfma_f32_16x16x32_bf16(ax1, *(const short8*)&sW[2][4 * 512 + lane * 8], s0, 0, 0, 0);
        s1 = __builtin_amdgcn_mfma_f32_16x16x32_bf16(a0, *(const short8*)&sW[1][1 * 512 + lane * 8], s1, 0, 0, 0);
        s1 = __builtin_amdgcn_mfma_f32_16x16x32_bf16(a1, *(const short8*)&sW[1][5 * 512 + lane * 8], s1, 0, 0, 0);
        s1 = __builtin_amdgcn_mfma_f32_16x16x32_bf16(ax0, *(const short8*)&sW[2][1 * 512 + lane * 8], s1, 0, 0, 0);
        s1 = __builtin_amdgcn_mfma_f32_16x16x32_bf16(ax1, *(const short8*)&sW[2][5 * 512 + lane * 8], s1, 0, 0, 0);
        s2 = __builtin_amdgcn_mfma_f32_16x16x32_bf16(a0, *(const short8*)&sW[1][2 * 512 + lane * 8], s2, 0, 0, 0);
        s2 = __builtin_amdgcn_mfma_f32_16x16x32_bf16(a1, *(const short8*)&sW[1][6 * 512 + lane * 8], s2, 0, 0, 0);
        s2 = __builtin_amdgcn_mfma_f32_16x16x32_bf16(ax0, *(const short8*)&sW[2][2 * 512 + lane * 8], s2, 0, 0, 0);
        s2 = __builtin_amdgcn_mfma_f32_16x16x32_bf16(ax1, *(const short8*)&sW[2][6 * 512 + lane * 8], s2, 0, 0, 0);
        s3 = __builtin_amdgcn_mfma_f32_16x16x32_bf16(a0, *(const short8*)&sW[1][3 * 512 + lane * 8], s3, 0, 0, 0);
        s3 = __builtin_amdgcn_mfma_f32_16x16x32_bf16(a1, *(const short8*)&sW[1][7 * 512 + lane * 8], s3, 0, 0, 0);
        s3 = __builtin_amdgcn_mfma_f32_16x16x32_bf16(ax0, *(const short8*)&sW[2][3 * 512 + lane * 8], s3, 0, 0, 0);
        s3 = __builtin_amdgcn_mfma_f32_16x16x32_bf16(ax1, *(const short8*)&sW[2][7 * 512 + lane * 8], s3, 0, 0, 0);
        floatx4 stl[4] = {s0, s1, s2, s3};
        #pragma unroll
        for (int nt = 0; nt < 4; ++nt) {
            float bs = bl1[nt * 16 + n16];
            #pragma unroll
            for (int r = 0; r < 4; ++r) {
                int node = base + quad * 4 + r;
                if (node < N)
                    buf1[(size_t)node * 128 + 64 + nt * 16 + n16] = f2bf(fmaxf(stl[nt][r] + bs, 0.f));
            }
        }
    }
}

// Layer-2 GEMMs + LN + concat-proj via MFMA (proven in R8).
__launch_bounds__(512, 1)
__global__ void k_gemm2(const unsigned short* __restrict__ agg,
                        const unsigned short* __restrict__ buf1,
                        const float* __restrict__ W2, const float* __restrict__ b2,
                        const float* __restrict__ Wl2, const float* __restrict__ bl2,
                        const float* __restrict__ Wr2,
                        const float* __restrict__ lngG, const float* __restrict__ lnbG,
                        const float* __restrict__ lngS, const float* __restrict__ lnbS,
                        const float* __restrict__ Pw, const float* __restrict__ Pb,
                        float* __restrict__ out, int N) {
    alignas(16) __shared__ unsigned short sW[3][4096];
    alignas(16) __shared__ unsigned short sP[8192];
    alignas(16) __shared__ unsigned short sT[8][16 * 132];
    int t = threadIdx.x;
    for (int i = t; i < 1536; i += 512) {
        int m = i >> 9;
        int rem = i & 511;
        int f = rem >> 6;
        int L = rem & 63;
        int kb = (f >> 2) * 32 + (L >> 4) * 8;
        int o = (f & 3) * 16 + (L & 15);
        const float* Wsrc = (m == 0) ? W2 : (m == 1) ? Wl2 : Wr2;
        unsigned short* dst = &sW[m][f * 512 + L * 8];
        #pragma unroll
        for (int j = 0; j < 8; ++j) dst[j] = f2bf(Wsrc[(kb + j) * 64 + o]);
    }
    for (int i = t; i < 1024; i += 512) {
        int f = i >> 6;
        int L = i & 63;
        int kb = (f >> 2) * 32 + (L >> 4) * 8;
        int o = (f & 3) * 16 + (L & 15);
        unsigned short* dst = &sP[f * 512 + L * 8];
        #pragma unroll
        for (int j = 0; j < 8; ++j) dst[j] = f2bf(Pw[(kb + j) * 64 + o]);
    }
    __syncthreads();

    int lane = t & 63;
    int wave = t >> 6;
    int quad = lane >> 4;
    int n16 = lane & 15;
    int base = blockIdx.x * 128 + wave * 16;
    if (base >= N) return;
    int nm = base + n16;
    if (nm >= N) nm = N - 1;
    const unsigned short* ar = agg + (size_t)nm * 128;
    const unsigned short* br = buf1 + (size_t)nm * 128;
    unsigned short* tw = &sT[wave][0];

    {
        short8 a0 = *(const short8*)(ar + quad * 8);
        short8 a1 = *(const short8*)(ar + 32 + quad * 8);
        floatx4 c0 = {0.f, 0.f, 0.f, 0.f}, c1 = c0, c2 = c0, c3 = c0;
        c0 = __builtin_amdgcn_mfma_f32_16x16x32_bf16(a0, *(const short8*)&sW[0][0 * 512 + lane * 8], c0, 0, 0, 0);
        c0 = __builtin_amdgcn_mfma_f32_16x16x32_bf16(a1, *(const short8*)&sW[0][4 * 512 + lane * 8], c0, 0, 0, 0);
        c1 = __builtin_amdgcn_mfma_f32_16x16x32_bf16(a0, *(const short8*)&sW[0][1 * 512 + lane * 8], c1, 0, 0, 0);
        c1 = __builtin_amdgcn_mfma_f32_16x16x32_bf16(a1, *(const short8*)&sW[0][5 * 512 + lane * 8], c1, 0, 0, 0);
        c2 = __builtin_amdgcn_mfma_f32_16x16x32_bf16(a0, *(const short8*)&sW[0][2 * 512 + lane * 8], c2, 0, 0, 0);
        c2 = __builtin_amdgcn_mfma_f32_16x16x32_bf16(a1, *(const short8*)&sW[0][6 * 512 + lane * 8], c2, 0, 0, 0);
        c3 = __builtin_amdgcn_mfma_f32_16x16x32_bf16(a0, *(const short8*)&sW[0][3 * 512 + lane * 8], c3, 0, 0, 0);
        c3 = __builtin_amdgcn_mfma_f32_16x16x32_bf16(a1, *(const short8*)&sW[0][7 * 512 + lane * 8], c3, 0, 0, 0);

        float bv0 = b2[n16], bv1 = b2[16 + n16], bv2 = b2[32 + n16], bv3 = b2[48 + n16];
        float gv0 = lngG[n16], gv1 = lngG[16 + n16], gv2 = lngG[32 + n16], gv3 = lngG[48 + n16];
        float ev0 = lnbG[n16], ev1 = lnbG[16 + n16], ev2 = lnbG[32 + n16], ev3 = lnbG[48 + n16];
        #pragma unroll
        for (int r = 0; r < 4; ++r) {
            float z0 = c0[r] + bv0, z1 = c1[r] + bv1, z2 = c2[r] + bv2, z3 = c3[r] + bv3;
            float s = red16(z0 + z1 + z2 + z3);
            float q = red16(z0 * z0 + z1 * z1 + z2 * z2 + z3 * z3);
            float mu = s * (1.0f / 64.0f);
            float var = fmaxf(q * (1.0f / 64.0f) - mu * mu, 0.0f);
            float rs = rsqrtf(var + 1e-5f);
            unsigned short* row = tw + (quad * 4 + r) * 132;
            row[n16]      = f2bf((z0 - mu) * rs * gv0 + ev0);
            row[16 + n16] = f2bf((z1 - mu) * rs * gv1 + ev1);
            row[32 + n16] = f2bf((z2 - mu) * rs * gv2 + ev2);
            row[48 + n16] = f2bf((z3 - mu) * rs * gv3 + ev3);
        }
    }

    {
        short8 a0 = *(const short8*)(ar + 64 + quad * 8);
        short8 a1 = *(const short8*)(ar + 96 + quad * 8);
        short8 v0 = *(const short8*)(br + 64 + quad * 8);
        short8 v1 = *(const short8*)(br + 96 + quad * 8);
        floatx4 c0 = {0.f, 0.f, 0.f, 0.f}, c1 = c0, c2 = c0, c3 = c0;
        c0 = __builtin_amdgcn_mfma_f32_16x16x32_bf16(a0, *(const short8*)&sW[1][0 * 512 + lane * 8], c0, 0, 0, 0);
        c0 = __builtin_amdgcn_mfma_f32_16x16x32_bf16(a1, *(const short8*)&sW[1][4 * 512 + lane * 8], c0, 0, 0, 0);
        c0 = __builtin_amdgcn_mfma_f32_16x16x32_bf16(v0, *(const short8*)&sW[2][0 * 512 + lane * 8], c0, 0, 0, 0);
        c0 = __builtin_amdgcn_mfma_f32_16x16x32_bf16(v1, *(const short8*)&sW[2][4 * 512 + lane * 8], c0, 0, 0, 0);
        c1 = __builtin_amdgcn_mfma_f32_16x16x32_bf16(a0, *(const short8*)&sW[1][1 * 512 + lane * 8], c1, 0, 0, 0);
        c1 = __builtin_amdgcn_mfma_f32_16x16x32_bf16(a1, *(const short8*)&sW[1][5 * 512 + lane * 8], c1, 0, 0, 0);
        c1 = __builtin_amdgcn_mfma_f32_16x16x32_bf16(v0, *(const short8*)&sW[2][1 * 512 + lane * 8], c1, 0, 0, 0);
        c1 = __builtin_amdgcn_mfma_f32_16x16x32_bf16(v1, *(const short8*)&sW[2][5 * 512 + lane * 8], c1, 0, 0, 0);
        c2 = __builtin_amdgcn_mfma_f32_16x16x32_bf16(a0, *(const short8*)&sW[1][2 * 512 + lane * 8], c2, 0, 0, 0);
        c2 = __builtin_amdgcn_mfma_f32_16x16x32_bf16(a1, *(const short8*)&sW[1][6 * 512 + lane * 8], c2, 0, 0, 0);
        c2 = __builtin_amdgcn_mfma_f32_16x16x32_bf16(v0, *(const short8*)&sW[2][2 * 512 + lane * 8], c2, 0, 0, 0);
        c2 = __builtin_amdgcn_mfma_f32_16x16x32_bf16(v1, *(const short8*)&sW[2][6 * 512 + lane * 8], c2, 0, 0, 0);
        c3 = __builtin_amdgcn_mfma_f32_16x16x32_bf16(a0, *(const short8*)&sW[1][3 * 512 + lane * 8], c3, 0, 0, 0);
        c3 = __builtin_amdgcn_mfma_f32_16x16x32_bf16(a1, *(const short8*)&sW[1][7 * 512 + lane * 8], c3, 0, 0, 0);
        c3 = __builtin_amdgcn_mfma_f32_16x16x32_bf16(v0, *(const short8*)&sW[2][3 * 512 + lane * 8], c3, 0, 0, 0);
        c3 = __builtin_amdgcn_mfma_f32_16x16x32_bf16(v1, *(const short8*)&sW[2][7 * 512 + lane * 8], c3, 0, 0, 0);

        float bv0 = bl2[n16], bv1 = bl2[16 + n16], bv2 = bl2[32 + n16], bv3 = bl2[48 + n16];
        float gv0 = lngS[n16], gv1 = lngS[16 + n16], gv2 = lngS[32 + n16], gv3 = lngS[48 + n16];
        float ev0 = lnbS[n16], ev1 = lnbS[16 + n16], ev2 = lnbS[32 + n16], ev3 = lnbS[48 + n16];
        #pragma unroll
        for (int r = 0; r < 4; ++r) {
            float z0 = c0[r] + bv0, z1 = c1[r] + bv1, z2 = c2[r] + bv2, z3 = c3[r] + bv3;
            float s = red16(z0 + z1 + z2 + z3);
            float q = red16(z0 * z0 + z1 * z1 + z2 * z2 + z3 * z3);
            float mu = s * (1.0f / 64.0f);
            float var = fmaxf(q * (1.0f / 64.0f) - mu * mu, 0.0f);
            float rs = rsqrtf(var + 1e-5f);
            unsigned short* row = tw + (quad * 4 + r) * 132 + 64;
            row[n16]      = f2bf((z0 - mu) * rs * gv0 + ev0);
            row[16 + n16] = f2bf((z1 - mu) * rs * gv1 + ev1);
            row[32 + n16] = f2bf((z2 - mu) * rs * gv2 + ev2);
            row[48 + n16] = f2bf((z3 - mu) * rs * gv3 + ev3);
        }
    }

    floatx4 o0 = {0.f, 0.f, 0.f, 0.f}, o1 = o0, o2 = o0, o3 = o0;
    #pragma unroll
    for (int ks = 0; ks < 4; ++ks) {
        const unsigned short* ap = tw + n16 * 132 + ks * 32 + quad * 8;
        short4v lo = *(const short4v*)ap;
        short4v hi = *(const short4v*)(ap + 4);
        short8 af;
        af[0] = lo[0]; af[1] = lo[1]; af[2] = lo[2]; af[3] = lo[3];
        af[4] = hi[0]; af[5] = hi[1]; af[6] = hi[2]; af[7] = hi[3];
        o0 = __builtin_amdgcn_mfma_f32_16x16x32_bf16(af, *(const short8*)&sP[(ks * 4 + 0) * 512 + lane * 8], o0, 0, 0, 0);
        o1 = __builtin_amdgcn_mfma_f32_16x16x32_bf16(af, *(const short8*)&sP[(ks * 4 + 1) * 512 + lane * 8], o1, 0, 0, 0);
        o2 = __builtin_amdgcn_mfma_f32_16x16x32_bf16(af, *(const short8*)&sP[(ks * 4 + 2) * 512 + lane * 8], o2, 0, 0, 0);
        o3 = __builtin_amdgcn_mfma_f32_16x16x32_bf16(af, *(const short8*)&sP[(ks * 4 + 3) * 512 + lane * 8], o3, 0, 0, 0);
    }
    float p0 = Pb[n16], p1 = Pb[16 + n16], p2 = Pb[32 + n16], p3 = Pb[48 + n16];
    floatx4 ot[4] = {o0, o1, o2, o3};
    float pv[4] = {p0, p1, p2, p3};
    #pragma unroll
    for (int nt = 0; nt < 4; ++nt) {
        #pragma unroll
        for (int r = 0; r < 4; ++r) {
            int node = base + quad * 4 + r;
            if (node < N) out[(size_t)node * 64 + nt * 16 + n16] = ot[nt][r] + pv[nt];
        }
    }
}

extern "C" void kernel_launch(void* const* d_in, const int* in_sizes, int n_in,
                              void* d_out, int out_size, void* d_ws, size_t ws_size,
                              hipStream_t stream) {
    const float* x        = (const float*)d_in[0];
    const int*   ei       = (const int*)d_in[1];
    const float* gcn_w1   = (const float*)d_in[2];
    const float* gcn_b1   = (const float*)d_in[3];
    const float* gcn_w2   = (const float*)d_in[4];
    const float* gcn_b2   = (const float*)d_in[5];
    const float* sage_wl1 = (const float*)d_in[6];
    const float* sage_bl1 = (const float*)d_in[7];
    const float* sage_wr1 = (const float*)d_in[8];
    const float* sage_wl2 = (const float*)d_in[9];
    const float* sage_bl2 = (const float*)d_in[10];
    const float* sage_wr2 = (const float*)d_in[11];
    const float* gcn_ln_g = (const float*)d_in[12];
    const float* gcn_ln_b = (const float*)d_in[13];
    const float* sage_ln_g = (const float*)d_in[14];
    const float* sage_ln_b = (const float*)d_in[15];
    const float* proj_w   = (const float*)d_in[16];
    const float* proj_b   = (const float*)d_in[17];
    float* out = (float*)d_out;

    const int N = in_sizes[0] / 64;
    const int E = in_sizes[1] / 2;
    const int G = (N + 15) / 16;
    const int Bg = (G + SCAN_CHUNK - 1) / SCAN_CHUNK;

    char* w = (char*)d_ws;
    size_t off = 0;
    auto alloc = [&](size_t bytes) -> void* {
        void* p = w + off;
        off = (off + bytes + 255) & ~(size_t)255;
        return p;
    };
    int*            cnt       = (int*)alloc((size_t)N * 4);
    int*            offs16    = (int*)alloc((size_t)(G + 1) * 4);
    float*          dinv      = (float*)alloc((size_t)N * 4);
    int*            blockSums = (int*)alloc((size_t)(Bg + 1) * 4);
    int*            cnt16     = (int*)alloc((size_t)G * 4);
    int*            csr       = (int*)alloc((size_t)(E + 16 * G + 64) * 4);
    unsigned int*   pk        = (unsigned int*)alloc((size_t)(E + 16 * G + 64) * 4);
    unsigned int*   counts    = (unsigned int*)alloc((size_t)NB * G * 4);
    unsigned short* agg       = (unsigned short*)alloc((size_t)N * 128 * 2);
    unsigned short* buf1      = (unsigned short*)alloc((size_t)N * 128 * 2);
    unsigned short* xb        = (unsigned short*)alloc((size_t)N * 64 * 2);
    (void)n_in; (void)out_size; (void)ws_size;

    k_hist<<<NB, 256, 0, stream>>>(ei, E, G, counts, x, xb, N * 64);
    k_colsum<<<(G + 255) / 256, 256, 0, stream>>>(counts, G, cnt16);
    k_gr<<<Bg, 256, 0, stream>>>(cnt16, G, blockSums);
    k_scan_spine<<<1, 64, 0, stream>>>(blockSums, Bg);
    k_gw<<<Bg, 256, 0, stream>>>(cnt16, G, blockSums, offs16);
    k_bases<<<(G + 255) / 256, 256, 0, stream>>>(counts, G, offs16);
    k_scatter<<<NB, 256, 0, stream>>>(ei, E, G, counts, csr, pk);
    k_degself<<<(G + 3) / 4, 256, 0, stream>>>(offs16, G, N, cnt, dinv, csr, pk);
    k_weights<<<(G + 3) / 4, 256, 0, stream>>>(csr, offs16, G, N, dinv, pk);

    k_gatherM<64><<<(N + 31) / 32, 256, 0, stream>>>(xb, csr, pk, offs16, cnt, agg, N);
    k_gemm1<<<(N + 127) / 128, 512, 0, stream>>>(agg, xb, gcn_w1, gcn_b1,
                                                 sage_wl1, sage_bl1, sage_wr1, buf1, N);
    k_gatherM<128><<<(N + 31) / 32, 256, 0, stream>>>(buf1, csr, pk, offs16, cnt, agg, N);
    k_gemm2<<<(N + 127) / 128, 512, 0, stream>>>(agg, buf1, gcn_w2, gcn_b2,
                                                 sage_wl2, sage_bl2, sage_wr2,
                                                 gcn_ln_g, gcn_ln_b, sage_ln_g, sage_ln_b,
                                                 proj_w, proj_b, out, N);
}